// Round 1
// baseline (77617.664 us; speedup 1.0000x reference)
//
#include <hip/hip_runtime.h>
#include <hip/hip_cooperative_groups.h>
#include <math.h>

namespace cg = cooperative_groups;

#define NROWS 16384
#define KC    1024
#define NBLK  512
#define NTHR  256
#define WPB   4      // waves per block
#define RPW   8      // rows per wave = 16384 / (512*4)
#define CPB   2      // regular columns owned per block
#define VSTR  1056   // padded stride for (K+1)-length vectors / z partials

__device__ __forceinline__ float wave_sum(float v) {
#pragma unroll
  for (int o = 32; o > 0; o >>= 1) v += __shfl_xor(v, o, 64);
  return v;
}
__device__ __forceinline__ float wave_max(float v) {
#pragma unroll
  for (int o = 32; o > 0; o >>= 1) v = fmaxf(v, __shfl_xor(v, o, 64));
  return v;
}

// One cooperative kernel runs the whole Sinkhorn loop.
// Q[:, 0:1024] lives in d_out; the appended column (cost=0) lives in ws (qlast).
__global__ __launch_bounds__(NTHR, 2)
void sk_coop(const float* __restrict__ X, float* __restrict__ Q, float* __restrict__ ws)
{
  cg::grid_group grid = cg::this_grid();
  const int g    = blockIdx.x;
  const int tid  = threadIdx.x;
  const int wv   = tid >> 6;
  const int lane = tid & 63;
  const int row0 = (g * WPB + wv) * RPW;

  float* qlast = ws;                      // [N]
  float* xmx   = qlast + NROWS;           // [N] row max of logits
  float* lrw   = xmx + NROWS;             // [N] log(sum(exp(x-max)))
  float* aarr  = lrw + NROWS;             // [N]
  float* uarr  = aarr + NROWS;            // [N]
  float* barr  = uarr + NROWS;            // [K+1] (padded VSTR)
  float* varr  = barr + VSTR;             // 2 ping-pong buffers [K+1]
  float* warr  = varr + 2 * VSTR;         // [K]
  float* zpart = warr + VSTR;             // [NBLK][VSTR]
  float* amaxp = zpart + (size_t)NBLK * VSTR;  // [NBLK]
  float* bmaxp = amaxp + NBLK;                 // [NBLK]
  float* errp  = bmaxp + NBLK;                 // [NBLK]

  __shared__ float ldsz[WPB * KC];
  __shared__ float ldss[32];

  const float FI   = (float)(1.0 / 1.1);        // gamma/(gamma+eps)
  const float FIM1 = (float)(1.0 / 1.1 - 1.0);
  const float TINY = 1.1920928955078125e-07f;   // float32 eps
  const float PA   = 1.0f / 16384.0f;
  const float PBJ  = 0.5f / 1024.0f;            // rho/k
  const float PBL  = 0.5f;                      // 1-rho
  const float EPSF = 0.1f;

  // ---------------- init ----------------
  if (tid < CPB) {
    const int j = g * CPB + tid;
    barr[j] = 1.0f / 1025.0f;
    varr[j] = 0.0f;
    warr[j] = 1.0f;
  }
  if (g == NBLK - 1 && tid == CPB) {
    barr[KC] = 1.0f / 1025.0f;
    varr[KC] = 0.0f;
  }
  for (int r = 0; r < RPW; ++r) {
    const int i = row0 + r;
    const float* xr = X + (size_t)i * KC;
    float x[16];
#pragma unroll
    for (int c = 0; c < 4; ++c) {
      const float4 t = *reinterpret_cast<const float4*>(xr + c * 256 + lane * 4);
      x[c*4+0] = t.x; x[c*4+1] = t.y; x[c*4+2] = t.z; x[c*4+3] = t.w;
    }
    float mx = -INFINITY;
#pragma unroll
    for (int e = 0; e < 16; ++e) mx = fmaxf(mx, x[e]);
    mx = wave_max(mx);
    float s = 0.0f;
#pragma unroll
    for (int e = 0; e < 16; ++e) s += expf(x[e] - mx);
    s = wave_sum(s);
    const float L = logf(s);
    if (lane == 0) { xmx[i] = mx; lrw[i] = L; uarr[i] = 0.0f; qlast[i] = 1.0f; }
    float* qr = Q + (size_t)i * KC;
#pragma unroll
    for (int c = 0; c < 4; ++c) {
      float4 o;
      o.x = expf(((x[c*4+0] - mx) - L) / EPSF);
      o.y = expf(((x[c*4+1] - mx) - L) / EPSF);
      o.z = expf(((x[c*4+2] - mx) - L) / EPSF);
      o.w = expf(((x[c*4+3] - mx) - L) / EPSF);
      *reinterpret_cast<float4*>(qr + c * 256 + lane * 4) = o;
    }
  }
  __threadfence();
  grid.sync();

  // ---------------- main loop ----------------
  int it = 0, vp = 0, stab = 0;
  float errv = 1.0f;

  while (true) {
    if (it > 0) {
      // every block redundantly reduces the decision (deterministic, identical)
      if (wv == 0) {
        float e2 = 0.0f, am = -INFINITY, bm = -INFINITY;
        for (int p = lane; p < NBLK; p += 64) {
          e2 += errp[p];
          am = fmaxf(am, amaxp[p]);
          bm = fmaxf(bm, bmaxp[p]);
        }
        e2 = wave_sum(e2); am = wave_max(am); bm = wave_max(bm);
        if (lane == 0) { ldss[0] = sqrtf(e2); ldss[1] = fmaxf(am, bm); }
      }
      __syncthreads();
      errv = ldss[0];
      stab = (ldss[1] > 1e8f) ? 1 : 0;
      __syncthreads();
    }
    if (!(errv > 1e-10f && it < 1000)) break;

    float zac[16];
#pragma unroll
    for (int e = 0; e < 16; ++e) zac[e] = 0.0f;
    float zl = 0.0f;
    float amx = -INFINITY;

    if (!stab) {
      // ---- P1 normal: y = Q b ; a = Pa/y ; accumulate z = Q^T a ----
      float bf[16];
#pragma unroll
      for (int c = 0; c < 4; ++c) {
        const float4 t = *reinterpret_cast<const float4*>(barr + c * 256 + lane * 4);
        bf[c*4+0] = t.x; bf[c*4+1] = t.y; bf[c*4+2] = t.z; bf[c*4+3] = t.w;
      }
      const float bl = barr[KC];
      for (int r = 0; r < RPW; ++r) {
        const int i = row0 + r;
        const float* qr = Q + (size_t)i * KC;
        float q[16];
#pragma unroll
        for (int c = 0; c < 4; ++c) {
          const float4 t = *reinterpret_cast<const float4*>(qr + c * 256 + lane * 4);
          q[c*4+0] = t.x; q[c*4+1] = t.y; q[c*4+2] = t.z; q[c*4+3] = t.w;
        }
        float d = 0.0f;
#pragma unroll
        for (int e = 0; e < 16; ++e) d = fmaf(q[e], bf[e], d);
        const float ql = qlast[i];
        const float y  = wave_sum(d) + ql * bl;
        const float ai = PA / y;
        if (lane == 0) aarr[i] = ai;
        amx = fmaxf(amx, ai);
#pragma unroll
        for (int e = 0; e < 16; ++e) zac[e] = fmaf(ai, q[e], zac[e]);
        zl = fmaf(ai, ql, zl);
      }
    } else {
      // ---- P1 with deferred stabilization: rewrite Q from logits, b := ones ----
      if (tid < CPB) {
        const int j = g * CPB + tid;
        const float bj = barr[j];
        varr[(vp ^ 1) * VSTR + j] = varr[vp * VSTR + j] + EPSF * logf(bj + TINY);
        warr[j] = warr[j] * powf(bj, FIM1);
      }
      if (g == NBLK - 1 && tid == CPB) {
        const float bj = barr[KC];
        varr[(vp ^ 1) * VSTR + KC] = varr[vp * VSTR + KC] + EPSF * logf(bj + TINY);
      }
      float v2f[16];
#pragma unroll
      for (int c = 0; c < 4; ++c) {
#pragma unroll
        for (int e = 0; e < 4; ++e) {
          const int j = c * 256 + lane * 4 + e;
          v2f[c*4+e] = varr[vp * VSTR + j] + EPSF * logf(barr[j] + TINY);
        }
      }
      const float v2l = varr[vp * VSTR + KC] + EPSF * logf(barr[KC] + TINY);
      for (int r = 0; r < RPW; ++r) {
        const int i = row0 + r;
        const float u2 = uarr[i] + EPSF * logf(aarr[i]);
        if (lane == 0) uarr[i] = u2;
        const float mi = xmx[i], Li = lrw[i];
        const float* xr = X + (size_t)i * KC;
        float q[16];
#pragma unroll
        for (int c = 0; c < 4; ++c) {
          const float4 t = *reinterpret_cast<const float4*>(xr + c * 256 + lane * 4);
          q[c*4+0] = t.x; q[c*4+1] = t.y; q[c*4+2] = t.z; q[c*4+3] = t.w;
        }
#pragma unroll
        for (int e = 0; e < 16; ++e) {
          const float cost = Li - (q[e] - mi);      // -log_softmax
          q[e] = expf((u2 - cost + v2f[e]) / EPSF);
        }
        float* qr = Q + (size_t)i * KC;
#pragma unroll
        for (int c = 0; c < 4; ++c) {
          float4 o;
          o.x = q[c*4+0]; o.y = q[c*4+1]; o.z = q[c*4+2]; o.w = q[c*4+3];
          *reinterpret_cast<float4*>(qr + c * 256 + lane * 4) = o;
        }
        float d = 0.0f;
#pragma unroll
        for (int e = 0; e < 16; ++e) d += q[e];
        const float ql = expf((u2 + v2l) / EPSF);
        if (lane == 0) qlast[i] = ql;
        const float y  = wave_sum(d) + ql;          // b == ones
        const float ai = PA / y;
        if (lane == 0) aarr[i] = ai;
        amx = fmaxf(amx, ai);
#pragma unroll
        for (int e = 0; e < 16; ++e) zac[e] = fmaf(ai, q[e], zac[e]);
        zl = fmaf(ai, ql, zl);
      }
      vp ^= 1;
    }

    // ---- block-level z reduction (deterministic order) -> zpart[g][*] ----
    __syncthreads();
#pragma unroll
    for (int c = 0; c < 4; ++c) {
      float4 o;
      o.x = zac[c*4+0]; o.y = zac[c*4+1]; o.z = zac[c*4+2]; o.w = zac[c*4+3];
      *reinterpret_cast<float4*>(ldsz + wv * KC + c * 256 + lane * 4) = o;
    }
    const float wamx = wave_max(amx);
    if (lane == 0) { ldss[8 + wv] = zl; ldss[16 + wv] = wamx; }
    __syncthreads();
    {
      float4 a0 = *reinterpret_cast<const float4*>(ldsz + 0 * KC + tid * 4);
      const float4 a1 = *reinterpret_cast<const float4*>(ldsz + 1 * KC + tid * 4);
      const float4 a2 = *reinterpret_cast<const float4*>(ldsz + 2 * KC + tid * 4);
      const float4 a3 = *reinterpret_cast<const float4*>(ldsz + 3 * KC + tid * 4);
      a0.x = ((a0.x + a1.x) + a2.x) + a3.x;
      a0.y = ((a0.y + a1.y) + a2.y) + a3.y;
      a0.z = ((a0.z + a1.z) + a2.z) + a3.z;
      a0.w = ((a0.w + a1.w) + a2.w) + a3.w;
      *reinterpret_cast<float4*>(zpart + (size_t)g * VSTR + tid * 4) = a0;
    }
    if (tid == 0) {
      zpart[(size_t)g * VSTR + KC] = ((ldss[8] + ldss[9]) + ldss[10]) + ldss[11];
      amaxp[g] = fmaxf(fmaxf(ldss[16], ldss[17]), fmaxf(ldss[18], ldss[19]));
    }
    __threadfence();
    grid.sync();

    // ---- P2: owned columns: z -> b (semi) ; err^2 & bmax partials ----
    {
      float e2 = 0.0f, bmx = -INFINITY;
      const int ncols = (g == NBLK - 1) ? 3 : 2;
      for (int cc = 0; cc < ncols; ++cc) {
        const int j = (cc < CPB) ? (g * CPB + cc) : KC;
        float part = zpart[(size_t)tid * VSTR + j] + zpart[(size_t)(tid + NTHR) * VSTR + j];
        part = wave_sum(part);
        if (lane == 0) ldss[24 + wv] = part;
        __syncthreads();
        if (tid == 0) {
          const float z    = ((ldss[24] + ldss[25]) + ldss[26]) + ldss[27];
          const float braw = ((j < KC) ? PBJ : PBL) / z;
          const float bnew = (j < KC) ? powf(braw, FI) * warr[j] : braw;
          const float lb   = stab ? 1.0f : barr[j];   // post-stab last_b == ones
          const float db   = bnew - lb;
          e2 += db * db;
          bmx = fmaxf(bmx, bnew);
          barr[j] = bnew;
        }
        __syncthreads();
      }
      if (tid == 0) { errp[g] = e2; bmaxp[g] = bmx; }
    }
    __threadfence();
    grid.sync();
    ++it;
  }

  // ---------------- final: plan[:, :-1] * n into d_out ----------------
  if (!stab) {
    float bf[16];
#pragma unroll
    for (int c = 0; c < 4; ++c) {
      const float4 t = *reinterpret_cast<const float4*>(barr + c * 256 + lane * 4);
      bf[c*4+0] = t.x; bf[c*4+1] = t.y; bf[c*4+2] = t.z; bf[c*4+3] = t.w;
    }
    for (int r = 0; r < RPW; ++r) {
      const int i  = row0 + r;
      const float ai = aarr[i];
      float* qr = Q + (size_t)i * KC;
#pragma unroll
      for (int c = 0; c < 4; ++c) {
        float4 t = *reinterpret_cast<const float4*>(qr + c * 256 + lane * 4);
        t.x = ((ai * t.x) * bf[c*4+0]) * 16384.0f;
        t.y = ((ai * t.y) * bf[c*4+1]) * 16384.0f;
        t.z = ((ai * t.z) * bf[c*4+2]) * 16384.0f;
        t.w = ((ai * t.w) * bf[c*4+3]) * 16384.0f;
        *reinterpret_cast<float4*>(qr + c * 256 + lane * 4) = t;
      }
    }
  } else {
    // pending stabilization at exit: plan = exp((u2 - cost + v2^T)/eps) * n
    float v2f[16];
#pragma unroll
    for (int c = 0; c < 4; ++c) {
#pragma unroll
      for (int e = 0; e < 4; ++e) {
        const int j = c * 256 + lane * 4 + e;
        v2f[c*4+e] = varr[vp * VSTR + j] + EPSF * logf(barr[j] + TINY);
      }
    }
    for (int r = 0; r < RPW; ++r) {
      const int i = row0 + r;
      const float u2 = uarr[i] + EPSF * logf(aarr[i]);
      const float mi = xmx[i], Li = lrw[i];
      const float* xr = X + (size_t)i * KC;
      float* qr = Q + (size_t)i * KC;
#pragma unroll
      for (int c = 0; c < 4; ++c) {
        const float4 t = *reinterpret_cast<const float4*>(xr + c * 256 + lane * 4);
        float4 o;
        o.x = expf((u2 - (Li - (t.x - mi)) + v2f[c*4+0]) / EPSF) * 16384.0f;
        o.y = expf((u2 - (Li - (t.y - mi)) + v2f[c*4+1]) / EPSF) * 16384.0f;
        o.z = expf((u2 - (Li - (t.z - mi)) + v2f[c*4+2]) / EPSF) * 16384.0f;
        o.w = expf((u2 - (Li - (t.w - mi)) + v2f[c*4+3]) / EPSF) * 16384.0f;
        *reinterpret_cast<float4*>(qr + c * 256 + lane * 4) = o;
      }
    }
  }
}

extern "C" void kernel_launch(void* const* d_in, const int* in_sizes, int n_in,
                              void* d_out, int out_size, void* d_ws, size_t ws_size,
                              hipStream_t stream)
{
  (void)in_sizes; (void)n_in; (void)out_size; (void)ws_size;
  const float* X = (const float*)d_in[0];
  float* Q  = (float*)d_out;
  float* ws = (float*)d_ws;
  void* args[3] = { (void*)&X, (void*)&Q, (void*)&ws };
  hipLaunchCooperativeKernel((const void*)sk_coop, dim3(NBLK), dim3(NTHR),
                             args, 0, stream);
}

// Round 2
// 43414.215 us; speedup vs baseline: 1.7878x; 1.7878x over previous
//
#include <hip/hip_runtime.h>
#include <math.h>

#define NROWS 16384
#define KC    1024
#define NBLK  256
#define NTHR  1024
#define WPB   16      // waves per block
#define RPW   4       // rows per wave = 16384 / (256*16)
#define CPB   4       // columns owned per block (block 255 also owns col 1024)
#define VSTR  1056    // padded stride for (K+1)-length z partial rows
#define NITER 1000

__device__ __forceinline__ float wave_sum(float v) {
#pragma unroll
  for (int o = 32; o > 0; o >>= 1) v += __shfl_xor(v, o, 64);
  return v;
}
__device__ __forceinline__ float wave_max(float v) {
#pragma unroll
  for (int o = 32; o > 0; o >>= 1) v = fmaxf(v, __shfl_xor(v, o, 64));
  return v;
}

// Two-level generation barrier over 256 blocks.
// ctrl layout (uints): c1[8] at 0,32,64,...,224 (128B apart); c2 at 288; gen at 320.
__device__ __forceinline__ void gbar(unsigned* ctrl, int g, int tid) {
  __syncthreads();   // all block lanes' global stores complete (vmcnt drained)
  if (tid == 0) {
    unsigned* gen = ctrl + 320;
    const unsigned gv = __hip_atomic_load(gen, __ATOMIC_RELAXED, __HIP_MEMORY_SCOPE_AGENT);
    unsigned* c1 = ctrl + (((unsigned)g) >> 5) * 32;
    bool released = false;
    const unsigned o1 = __hip_atomic_fetch_add(c1, 1u, __ATOMIC_ACQ_REL, __HIP_MEMORY_SCOPE_AGENT);
    if (o1 == 31u) {
      __hip_atomic_store(c1, 0u, __ATOMIC_RELAXED, __HIP_MEMORY_SCOPE_AGENT);
      unsigned* c2 = ctrl + 288;
      const unsigned o2 = __hip_atomic_fetch_add(c2, 1u, __ATOMIC_ACQ_REL, __HIP_MEMORY_SCOPE_AGENT);
      if (o2 == 7u) {
        __hip_atomic_store(c2, 0u, __ATOMIC_RELAXED, __HIP_MEMORY_SCOPE_AGENT);
        __hip_atomic_store(gen, gv + 1u, __ATOMIC_RELEASE, __HIP_MEMORY_SCOPE_AGENT);
        released = true;
      }
    }
    if (!released) {
      while (__hip_atomic_load(gen, __ATOMIC_RELAXED, __HIP_MEMORY_SCOPE_AGENT) == gv)
        __builtin_amdgcn_s_sleep(4);
      __builtin_amdgcn_fence(__ATOMIC_ACQUIRE, "agent");
    }
  }
  __syncthreads();
}

__device__ __forceinline__ int decide(const float* amaxp, const float* bmaxp,
                                      float* ldss, int wv, int lane) {
  if (wv == 0) {
    float am = -INFINITY, bm = -INFINITY;
#pragma unroll
    for (int k = 0; k < 4; ++k) {
      am = fmaxf(am, amaxp[lane + 64 * k]);
      bm = fmaxf(bm, bmaxp[lane + 64 * k]);
    }
    am = wave_max(am); bm = wave_max(bm);
    if (lane == 0) ldss[0] = fmaxf(am, bm);
  }
  __syncthreads();
  const int s = (ldss[0] > 1e8f) ? 1 : 0;
  __syncthreads();
  return s;
}

__global__ __launch_bounds__(NTHR, 4)
void sk_coop(const float* __restrict__ X, float* __restrict__ Q, void* __restrict__ wsv)
{
  const int g    = blockIdx.x;
  const int tid  = threadIdx.x;
  const int wv   = tid >> 6;
  const int lane = tid & 63;
  const int row0 = (g * WPB + wv) * RPW;

  unsigned* ctrl = (unsigned*)wsv;
  float* qlast = (float*)((char*)wsv + 2048);   // [N]
  float* xmx   = qlast + NROWS;                 // [N]
  float* lrw   = xmx + NROWS;                   // [N]
  float* aarr  = lrw + NROWS;                   // [N]
  float* uarr  = aarr + NROWS;                  // [N]
  float* barr  = uarr + NROWS;                  // [VSTR]
  float* varr  = barr + VSTR;                   // 2 ping-pong [VSTR]
  float* warr  = varr + 2 * VSTR;               // [VSTR]
  float* zpart = warr + VSTR;                   // [NBLK][VSTR]
  float* amaxp = zpart + (size_t)NBLK * VSTR;   // [NBLK]
  float* bmaxp = amaxp + NBLK;                  // [NBLK]

  __shared__ float ldsz[8 * KC];   // 32 KB z pair-reduce
  __shared__ float ldss[64];

  const float FI   = (float)(1.0 / 1.1);
  const float FIM1 = (float)(1.0 / 1.1 - 1.0);
  const float TINY = 1.1920928955078125e-07f;
  const float PA   = 1.0f / 16384.0f;
  const float PBJ  = 0.5f / 1024.0f;
  const float PBL  = 0.5f;
  const float EPSF = 0.1f;

  // ---------------- init ----------------
  if (tid < CPB) {
    const int j = g * CPB + tid;
    barr[j] = 1.0f / 1025.0f;
    varr[j] = 0.0f;
    warr[j] = 1.0f;
  }
  if (g == NBLK - 1 && tid == CPB) {
    barr[KC] = 1.0f / 1025.0f;
    varr[KC] = 0.0f;
  }
#pragma unroll
  for (int r = 0; r < RPW; ++r) {
    const int i = row0 + r;
    const float* xr = X + (size_t)i * KC + lane * 4;
    float x[16];
#pragma unroll
    for (int c = 0; c < 4; ++c) {
      const float4 t = *reinterpret_cast<const float4*>(xr + c * 256);
      x[c*4+0] = t.x; x[c*4+1] = t.y; x[c*4+2] = t.z; x[c*4+3] = t.w;
    }
    float mx = -INFINITY;
#pragma unroll
    for (int e = 0; e < 16; ++e) mx = fmaxf(mx, x[e]);
    mx = wave_max(mx);
    float s = 0.0f;
#pragma unroll
    for (int e = 0; e < 16; ++e) s += expf(x[e] - mx);
    s = wave_sum(s);
    const float L = logf(s);
    if (lane == 0) { xmx[i] = mx; lrw[i] = L; uarr[i] = 0.0f; qlast[i] = 1.0f; }
    float* qr = Q + (size_t)i * KC + lane * 4;
#pragma unroll
    for (int c = 0; c < 4; ++c) {
      float4 o;
      o.x = expf(((x[c*4+0] - mx) - L) / EPSF);
      o.y = expf(((x[c*4+1] - mx) - L) / EPSF);
      o.z = expf(((x[c*4+2] - mx) - L) / EPSF);
      o.w = expf(((x[c*4+3] - mx) - L) / EPSF);
      *reinterpret_cast<float4*>(qr + c * 256) = o;
    }
  }
  gbar(ctrl, g, tid);

  // ---------------- main loop: fixed 1000 iterations ----------------
  int vp = 0;
  for (int it = 0; it < NITER; ++it) {
    const int stab = (it > 0) ? decide(amaxp, bmaxp, ldss, wv, lane) : 0;

    float zac[16];
#pragma unroll
    for (int e = 0; e < 16; ++e) zac[e] = 0.0f;
    float zl = 0.0f;
    float amx = -INFINITY;

    if (!stab) {
      // ---- P1 normal: y = Q b ; a = Pa/y ; z += a_i * Q_i ----
      float bf[16];
#pragma unroll
      for (int c = 0; c < 4; ++c) {
        const float4 t = *reinterpret_cast<const float4*>(barr + c * 256 + lane * 4);
        bf[c*4+0] = t.x; bf[c*4+1] = t.y; bf[c*4+2] = t.z; bf[c*4+3] = t.w;
      }
      const float bl = barr[KC];
      float ql4[RPW];
#pragma unroll
      for (int r = 0; r < RPW; ++r) ql4[r] = qlast[row0 + r];

      const float* q0 = Q + (size_t)row0 * KC + lane * 4;
      float4 buf[2][4];
#pragma unroll
      for (int c = 0; c < 4; ++c) buf[0][c] = *reinterpret_cast<const float4*>(q0 + c * 256);
#pragma unroll
      for (int c = 0; c < 4; ++c) buf[1][c] = *reinterpret_cast<const float4*>(q0 + KC + c * 256);

#pragma unroll
      for (int r = 0; r < RPW; ++r) {
        float q[16];
#pragma unroll
        for (int c = 0; c < 4; ++c) {
          const float4 t = buf[r & 1][c];
          q[c*4+0] = t.x; q[c*4+1] = t.y; q[c*4+2] = t.z; q[c*4+3] = t.w;
        }
        if (r + 2 < RPW) {
#pragma unroll
          for (int c = 0; c < 4; ++c)
            buf[r & 1][c] = *reinterpret_cast<const float4*>(q0 + (size_t)(r + 2) * KC + c * 256);
        }
        float d = 0.0f;
#pragma unroll
        for (int e = 0; e < 16; ++e) d = fmaf(q[e], bf[e], d);
        const float y  = wave_sum(d) + ql4[r] * bl;
        const float ai = PA / y;
        if (lane == 0) aarr[row0 + r] = ai;
        amx = fmaxf(amx, ai);
#pragma unroll
        for (int e = 0; e < 16; ++e) zac[e] = fmaf(ai, q[e], zac[e]);
        zl = fmaf(ai, ql4[r], zl);
      }
    } else {
      // ---- P1 deferred stabilization: rewrite Q from logits; b := ones ----
      if (tid < CPB) {
        const int j = g * CPB + tid;
        const float bj = barr[j];
        varr[(vp ^ 1) * VSTR + j] = varr[vp * VSTR + j] + EPSF * logf(bj + TINY);
        warr[j] = warr[j] * powf(bj, FIM1);
      }
      if (g == NBLK - 1 && tid == CPB) {
        const float bj = barr[KC];
        varr[(vp ^ 1) * VSTR + KC] = varr[vp * VSTR + KC] + EPSF * logf(bj + TINY);
      }
      float v2f[16];
#pragma unroll
      for (int c = 0; c < 4; ++c) {
#pragma unroll
        for (int e = 0; e < 4; ++e) {
          const int j = c * 256 + lane * 4 + e;
          v2f[c*4+e] = varr[vp * VSTR + j] + EPSF * logf(barr[j] + TINY);
        }
      }
      const float v2l = varr[vp * VSTR + KC] + EPSF * logf(barr[KC] + TINY);
#pragma unroll
      for (int r = 0; r < RPW; ++r) {
        const int i = row0 + r;
        const float u2 = uarr[i] + EPSF * logf(aarr[i]);
        if (lane == 0) uarr[i] = u2;
        const float mi = xmx[i], Li = lrw[i];
        const float* xr = X + (size_t)i * KC + lane * 4;
        float q[16];
#pragma unroll
        for (int c = 0; c < 4; ++c) {
          const float4 t = *reinterpret_cast<const float4*>(xr + c * 256);
          q[c*4+0] = t.x; q[c*4+1] = t.y; q[c*4+2] = t.z; q[c*4+3] = t.w;
        }
#pragma unroll
        for (int e = 0; e < 16; ++e) {
          const float cost = Li - (q[e] - mi);
          q[e] = expf((u2 - cost + v2f[e]) / EPSF);
        }
        float* qr = Q + (size_t)i * KC + lane * 4;
#pragma unroll
        for (int c = 0; c < 4; ++c) {
          float4 o;
          o.x = q[c*4+0]; o.y = q[c*4+1]; o.z = q[c*4+2]; o.w = q[c*4+3];
          *reinterpret_cast<float4*>(qr + c * 256) = o;
        }
        float d = 0.0f;
#pragma unroll
        for (int e = 0; e < 16; ++e) d += q[e];
        const float ql = expf((u2 + v2l) / EPSF);
        if (lane == 0) qlast[i] = ql;
        const float y  = wave_sum(d) + ql;
        const float ai = PA / y;
        if (lane == 0) aarr[i] = ai;
        amx = fmaxf(amx, ai);
#pragma unroll
        for (int e = 0; e < 16; ++e) zac[e] = fmaf(ai, q[e], zac[e]);
        zl = fmaf(ai, ql, zl);
      }
      vp ^= 1;
    }

    // ---- z reduce: 16 waves -> 8 LDS rows -> 1 zpart row ----
    const float wamx = wave_max(amx);
    __syncthreads();
    if (wv < 8) {
#pragma unroll
      for (int c = 0; c < 4; ++c) {
        float4 o;
        o.x = zac[c*4+0]; o.y = zac[c*4+1]; o.z = zac[c*4+2]; o.w = zac[c*4+3];
        *reinterpret_cast<float4*>(ldsz + wv * KC + c * 256 + lane * 4) = o;
      }
    }
    if (lane == 0) { ldss[8 + wv] = zl; ldss[24 + wv] = wamx; }
    __syncthreads();
    if (wv >= 8) {
      float* dst = ldsz + (wv - 8) * KC + lane * 4;
#pragma unroll
      for (int c = 0; c < 4; ++c) {
        float4 t = *reinterpret_cast<float4*>(dst + c * 256);
        t.x += zac[c*4+0]; t.y += zac[c*4+1]; t.z += zac[c*4+2]; t.w += zac[c*4+3];
        *reinterpret_cast<float4*>(dst + c * 256) = t;
      }
    }
    __syncthreads();
    {
      float s = 0.0f;
#pragma unroll
      for (int w = 0; w < 8; ++w) s += ldsz[w * KC + tid];
      zpart[(size_t)g * VSTR + tid] = s;
    }
    if (tid == 0) {
      float zt = 0.0f;
#pragma unroll
      for (int w = 0; w < 16; ++w) zt += ldss[8 + w];
      zpart[(size_t)g * VSTR + KC] = zt;
      float am = ldss[24];
#pragma unroll
      for (int w = 1; w < 16; ++w) am = fmaxf(am, ldss[24 + w]);
      amaxp[g] = am;
    }
    gbar(ctrl, g, tid);

    // ---- P2: owned columns -> b (semi) ; bmax partial ----
    if (tid < 256) {
      const float4 zp = *reinterpret_cast<const float4*>(zpart + (size_t)tid * VSTR + g * 4);
      const float s0 = wave_sum(zp.x);
      const float s1 = wave_sum(zp.y);
      const float s2 = wave_sum(zp.z);
      const float s3 = wave_sum(zp.w);
      float sl = 0.0f;
      if (g == NBLK - 1) sl = wave_sum(zpart[(size_t)tid * VSTR + KC]);
      if (lane == 0) {
        ldss[40 + wv * 4 + 0] = s0; ldss[40 + wv * 4 + 1] = s1;
        ldss[40 + wv * 4 + 2] = s2; ldss[40 + wv * 4 + 3] = s3;
        ldss[56 + wv] = sl;
      }
    }
    __syncthreads();
    if (tid == 0) {
      float bmx = -INFINITY;
#pragma unroll
      for (int c = 0; c < 4; ++c) {
        const float z    = ((ldss[40 + c] + ldss[44 + c]) + ldss[48 + c]) + ldss[52 + c];
        const float bnew = powf(PBJ / z, FI) * warr[g * CPB + c];
        barr[g * CPB + c] = bnew;
        bmx = fmaxf(bmx, bnew);
      }
      if (g == NBLK - 1) {
        const float z  = ((ldss[56] + ldss[57]) + ldss[58]) + ldss[59];
        const float bn = PBL / z;
        barr[KC] = bn;
        bmx = fmaxf(bmx, bn);
      }
      bmaxp[g] = bmx;
    }
    gbar(ctrl, g, tid);
  }

  // ---------------- epilogue ----------------
  const int fstab = decide(amaxp, bmaxp, ldss, wv, lane);
  if (!fstab) {
    float bf[16];
#pragma unroll
    for (int c = 0; c < 4; ++c) {
      const float4 t = *reinterpret_cast<const float4*>(barr + c * 256 + lane * 4);
      bf[c*4+0] = t.x; bf[c*4+1] = t.y; bf[c*4+2] = t.z; bf[c*4+3] = t.w;
    }
#pragma unroll
    for (int r = 0; r < RPW; ++r) {
      const int i = row0 + r;
      const float ai = aarr[i];
      float* qr = Q + (size_t)i * KC + lane * 4;
#pragma unroll
      for (int c = 0; c < 4; ++c) {
        float4 t = *reinterpret_cast<const float4*>(qr + c * 256);
        t.x = ((ai * t.x) * bf[c*4+0]) * 16384.0f;
        t.y = ((ai * t.y) * bf[c*4+1]) * 16384.0f;
        t.z = ((ai * t.z) * bf[c*4+2]) * 16384.0f;
        t.w = ((ai * t.w) * bf[c*4+3]) * 16384.0f;
        *reinterpret_cast<float4*>(qr + c * 256) = t;
      }
    }
  } else {
    float v2f[16];
#pragma unroll
    for (int c = 0; c < 4; ++c) {
#pragma unroll
      for (int e = 0; e < 4; ++e) {
        const int j = c * 256 + lane * 4 + e;
        v2f[c*4+e] = varr[vp * VSTR + j] + EPSF * logf(barr[j] + TINY);
      }
    }
#pragma unroll
    for (int r = 0; r < RPW; ++r) {
      const int i = row0 + r;
      const float u2 = uarr[i] + EPSF * logf(aarr[i]);
      const float mi = xmx[i], Li = lrw[i];
      const float* xr = X + (size_t)i * KC + lane * 4;
      float* qr = Q + (size_t)i * KC + lane * 4;
#pragma unroll
      for (int c = 0; c < 4; ++c) {
        const float4 t = *reinterpret_cast<const float4*>(xr + c * 256);
        float4 o;
        o.x = expf((u2 - (Li - (t.x - mi)) + v2f[c*4+0]) / EPSF) * 16384.0f;
        o.y = expf((u2 - (Li - (t.y - mi)) + v2f[c*4+1]) / EPSF) * 16384.0f;
        o.z = expf((u2 - (Li - (t.z - mi)) + v2f[c*4+2]) / EPSF) * 16384.0f;
        o.w = expf((u2 - (Li - (t.w - mi)) + v2f[c*4+3]) / EPSF) * 16384.0f;
        *reinterpret_cast<float4*>(qr + c * 256) = o;
      }
    }
  }
}

extern "C" void kernel_launch(void* const* d_in, const int* in_sizes, int n_in,
                              void* d_out, int out_size, void* d_ws, size_t ws_size,
                              hipStream_t stream)
{
  (void)in_sizes; (void)n_in; (void)out_size; (void)ws_size;
  const float* X = (const float*)d_in[0];
  float* Q = (float*)d_out;
  // zero the barrier control block (counters + generation)
  hipMemsetAsync(d_ws, 0, 2048, stream);
  void* args[3] = { (void*)&X, (void*)&Q, (void*)&d_ws };
  hipLaunchCooperativeKernel((const void*)sk_coop, dim3(NBLK), dim3(NTHR),
                             args, 0, stream);
}

// Round 3
// 29355.450 us; speedup vs baseline: 2.6441x; 1.4789x over previous
//
#include <hip/hip_runtime.h>
#include <math.h>

#define NROWS 16384
#define KC    1024
#define NBLK  256
#define NTHR  1024
#define WPB   16      // waves per block
#define RPW   4       // rows per wave; 64 rows per block
#define CPB   4       // regular columns owned per block (block 255 also owns col 1024)
#define VSTR  1056    // padded stride for (K+1)-length vectors
#define NITER 1000

// relaxed agent-scope (device-coherent, cache-bypassing) access
#define AL(p)    __hip_atomic_load((p), __ATOMIC_RELAXED, __HIP_MEMORY_SCOPE_AGENT)
#define AS(p,v)  __hip_atomic_store((p), (v), __ATOMIC_RELAXED, __HIP_MEMORY_SCOPE_AGENT)

__device__ __forceinline__ float wave_sum(float v) {
#pragma unroll
  for (int o = 32; o > 0; o >>= 1) v += __shfl_xor(v, o, 64);
  return v;
}
__device__ __forceinline__ float wave_max(float v) {
#pragma unroll
  for (int o = 32; o > 0; o >>= 1) v = fmaxf(v, __shfl_xor(v, o, 64));
  return v;
}

// Fence-free two-level barrier. ctrl (uints): c1[8] at i*32, c2 at 288,
// gmax at 320, release flags[8] at 352+i*32. Flag value = seq*2 | stab.
__device__ __forceinline__ unsigned gbar(unsigned* ctrl, unsigned* flds,
                                         int g, int tid, unsigned seq, int isb2) {
  __syncthreads();   // each wave drains its vmem (incl. coherent stores) before arrival
  if (tid == 0) {
    unsigned fl;
    bool released = false;
    unsigned* c1 = ctrl + (((unsigned)g) >> 5) * 32;
    const unsigned o1 = __hip_atomic_fetch_add(c1, 1u, __ATOMIC_RELAXED, __HIP_MEMORY_SCOPE_AGENT);
    if (o1 == 31u) {
      AS(c1, 0u);
      asm volatile("s_waitcnt vmcnt(0)" ::: "memory");   // reset visible before signaling up
      unsigned* c2 = ctrl + 288;
      const unsigned o2 = __hip_atomic_fetch_add(c2, 1u, __ATOMIC_RELAXED, __HIP_MEMORY_SCOPE_AGENT);
      if (o2 == 7u) {
        unsigned stab = 0u;
        if (isb2) {
          const unsigned gm = AL(ctrl + 320);
          stab = (__uint_as_float(gm) > 1e8f) ? 1u : 0u;
          AS(ctrl + 320, 0u);
        }
        AS(c2, 0u);
        fl = seq * 2u + stab;
        asm volatile("s_waitcnt vmcnt(0)" ::: "memory"); // resets visible before release
#pragma unroll
        for (int i = 0; i < 8; ++i) AS(ctrl + 352 + i * 32, fl);
        flds[0] = fl;
        released = true;
      }
    }
    if (!released) {
      unsigned* myf = ctrl + 352 + (((unsigned)g) & 7u) * 32;
      for (;;) {
        fl = AL(myf);
        if (fl >= seq * 2u) break;
        __builtin_amdgcn_s_sleep(2);
      }
      flds[0] = fl;
    }
  }
  __syncthreads();
  return flds[0];
}

#define LOADR(dst, p)                                                    \
  { dst[0] = *reinterpret_cast<const float4*>((p));                      \
    dst[1] = *reinterpret_cast<const float4*>((p) + 256);                \
    dst[2] = *reinterpret_cast<const float4*>((p) + 512);                \
    dst[3] = *reinterpret_cast<const float4*>((p) + 768); }

__global__ __launch_bounds__(NTHR, 4)
void sk_coop(const float* __restrict__ X, float* __restrict__ Q, void* __restrict__ wsv)
{
  const int g    = blockIdx.x;
  const int tid  = threadIdx.x;
  const int wv   = tid >> 6;
  const int lane = tid & 63;
  const int row0 = (g * WPB + wv) * RPW;
  const unsigned rb = (((unsigned)g) & 7u) * VSTR;

  unsigned* ctrl = (unsigned*)wsv;
  float* varr  = (float*)((char*)wsv + 4096);   // [2*VSTR] dual potentials
  float* brep  = varr + 2 * VSTR;               // [8][VSTR] b replicas
  float* zpart = brep + 8 * VSTR;               // [NBLK][VSTR]

  __shared__ float ldsz[8 * KC];     // 32 KB z pair-reduce
  __shared__ float ldss[64];
  __shared__ float bstage[VSTR];
  __shared__ float vstage[VSTR];
  __shared__ float rq[64], rxm[64], rlr[64], ra[64], ru[64];  // per-row state
  __shared__ float wlds[CPB];
  __shared__ unsigned flds[1];

  const float FI   = (float)(1.0 / 1.1);
  const float FIM1 = (float)(1.0 / 1.1 - 1.0);
  const float TINY = 1.1920928955078125e-07f;
  const float PA   = 1.0f / 16384.0f;
  const float PBJ  = 0.5f / 1024.0f;
  const float PBL  = 0.5f;
  const float EPSF = 0.1f;

  // ---------------- init ----------------
  if (tid < CPB) {
    AS(&varr[g * CPB + tid], 0.0f);
    AS(&varr[VSTR + g * CPB + tid], 0.0f);
    wlds[tid] = 1.0f;
  }
  if (g == NBLK - 1 && tid == CPB) { AS(&varr[KC], 0.0f); AS(&varr[VSTR + KC], 0.0f); }
#pragma unroll
  for (int r = 0; r < RPW; ++r) {
    const int i  = row0 + r;
    const int lr = wv * RPW + r;
    const float* xr = X + (size_t)i * KC + lane * 4;
    float x[16];
#pragma unroll
    for (int c = 0; c < 4; ++c) {
      const float4 t = *reinterpret_cast<const float4*>(xr + c * 256);
      x[c*4+0] = t.x; x[c*4+1] = t.y; x[c*4+2] = t.z; x[c*4+3] = t.w;
    }
    float mx = -INFINITY;
#pragma unroll
    for (int e = 0; e < 16; ++e) mx = fmaxf(mx, x[e]);
    mx = wave_max(mx);
    float s = 0.0f;
#pragma unroll
    for (int e = 0; e < 16; ++e) s += expf(x[e] - mx);
    s = wave_sum(s);
    const float L = logf(s);
    if (lane == 0) { rxm[lr] = mx; rlr[lr] = L; ru[lr] = 0.0f; rq[lr] = 1.0f; }
    float* qr = Q + (size_t)i * KC + lane * 4;
#pragma unroll
    for (int c = 0; c < 4; ++c) {
      float4 o;
      o.x = expf(((x[c*4+0] - mx) - L) / EPSF);
      o.y = expf(((x[c*4+1] - mx) - L) / EPSF);
      o.z = expf(((x[c*4+2] - mx) - L) / EPSF);
      o.w = expf(((x[c*4+3] - mx) - L) / EPSF);
      *reinterpret_cast<float4*>(qr + c * 256) = o;
    }
  }
  // no global sync needed before iter 0: b(0) is a constant, Q rows are block-local

  // ---------------- main loop ----------------
  int vp = 0, stab = 0;
  unsigned seq = 0;
  const float* q0 = Q + (size_t)row0 * KC + lane * 4;

  for (int it = 0; it < NITER; ++it) {
    // ---- stage b (and v if stabilizing) into LDS ----
    if (it == 0) {
      bstage[tid] = 1.0f / 1025.0f;
      if (tid == 0) bstage[KC] = 1.0f / 1025.0f;
    } else {
      bstage[tid] = AL(&brep[rb + tid]);
      if (tid == 0) bstage[KC] = AL(&brep[rb + KC]);
    }

    float zac[16];
#pragma unroll
    for (int e = 0; e < 16; ++e) zac[e] = 0.0f;
    float zl = 0.0f, amx = -INFINITY;

    if (!stab) {
      float4 b0[4], b1[4], b2[4];
      LOADR(b0, q0);
      LOADR(b1, q0 + KC);
      LOADR(b2, q0 + 2 * KC);
      __syncthreads();
      float bf[16];
#pragma unroll
      for (int c = 0; c < 4; ++c) {
#pragma unroll
        for (int e = 0; e < 4; ++e) bf[c*4+e] = bstage[c * 256 + lane * 4 + e];
      }
      const float bl = bstage[KC];
#pragma unroll
      for (int r = 0; r < RPW; ++r) {
        const int lr = wv * RPW + r;
        float q[16];
        {
          const float4* bsrc = (r == 0) ? b0 : (r == 1) ? b1 : (r == 2) ? b2 : b0;
#pragma unroll
          for (int c = 0; c < 4; ++c) {
            const float4 t = bsrc[c];
            q[c*4+0] = t.x; q[c*4+1] = t.y; q[c*4+2] = t.z; q[c*4+3] = t.w;
          }
        }
        if (r == 0) LOADR(b0, q0 + 3 * KC);  // prefetch last row while computing
        float d = 0.0f;
#pragma unroll
        for (int e = 0; e < 16; ++e) d = fmaf(q[e], bf[e], d);
        const float ql = rq[lr];
        const float y  = wave_sum(d) + ql * bl;
        const float ai = PA / y;
        if (lane == 0) ra[lr] = ai;
        amx = fmaxf(amx, ai);
#pragma unroll
        for (int e = 0; e < 16; ++e) zac[e] = fmaf(ai, q[e], zac[e]);
        zl = fmaf(ai, ql, zl);
      }
    } else {
      // deferred stabilization: rewrite Q from logits; b := ones
      vstage[tid] = AL(&varr[vp * VSTR + tid]);
      if (tid == 0) vstage[KC] = AL(&varr[vp * VSTR + KC]);
      __syncthreads();
      if (tid < CPB) {
        const int j = g * CPB + tid;
        const float bj = bstage[j];
        AS(&varr[(vp ^ 1) * VSTR + j], vstage[j] + EPSF * logf(bj + TINY));
        wlds[tid] = wlds[tid] * powf(bj, FIM1);
      }
      if (g == NBLK - 1 && tid == CPB)
        AS(&varr[(vp ^ 1) * VSTR + KC], vstage[KC] + EPSF * logf(bstage[KC] + TINY));
      float v2f[16];
#pragma unroll
      for (int c = 0; c < 4; ++c) {
#pragma unroll
        for (int e = 0; e < 4; ++e) {
          const int j = c * 256 + lane * 4 + e;
          v2f[c*4+e] = vstage[j] + EPSF * logf(bstage[j] + TINY);
        }
      }
      const float v2l = vstage[KC] + EPSF * logf(bstage[KC] + TINY);
#pragma unroll
      for (int r = 0; r < RPW; ++r) {
        const int i  = row0 + r;
        const int lr = wv * RPW + r;
        const float u2 = ru[lr] + EPSF * logf(ra[lr]);
        if (lane == 0) ru[lr] = u2;
        const float mi = rxm[lr], Li = rlr[lr];
        const float* xr = X + (size_t)i * KC + lane * 4;
        float q[16];
#pragma unroll
        for (int c = 0; c < 4; ++c) {
          const float4 t = *reinterpret_cast<const float4*>(xr + c * 256);
          q[c*4+0] = t.x; q[c*4+1] = t.y; q[c*4+2] = t.z; q[c*4+3] = t.w;
        }
#pragma unroll
        for (int e = 0; e < 16; ++e) {
          const float cost = Li - (q[e] - mi);
          q[e] = expf((u2 - cost + v2f[e]) / EPSF);
        }
        float* qr = Q + (size_t)i * KC + lane * 4;
#pragma unroll
        for (int c = 0; c < 4; ++c) {
          float4 o;
          o.x = q[c*4+0]; o.y = q[c*4+1]; o.z = q[c*4+2]; o.w = q[c*4+3];
          *reinterpret_cast<float4*>(qr + c * 256) = o;
        }
        float d = 0.0f;
#pragma unroll
        for (int e = 0; e < 16; ++e) d += q[e];
        const float ql = expf((u2 + v2l) / EPSF);
        if (lane == 0) rq[lr] = ql;
        const float y  = wave_sum(d) + ql;
        const float ai = PA / y;
        if (lane == 0) ra[lr] = ai;
        amx = fmaxf(amx, ai);
#pragma unroll
        for (int e = 0; e < 16; ++e) zac[e] = fmaf(ai, q[e], zac[e]);
        zl = fmaf(ai, ql, zl);
      }
      vp ^= 1;
    }

    // ---- z reduce: 16 waves -> 8 LDS rows -> 1 zpart row (coherent stores) ----
    const float wamx = wave_max(amx);
    __syncthreads();
    if (wv < 8) {
#pragma unroll
      for (int c = 0; c < 4; ++c) {
        float4 o;
        o.x = zac[c*4+0]; o.y = zac[c*4+1]; o.z = zac[c*4+2]; o.w = zac[c*4+3];
        *reinterpret_cast<float4*>(ldsz + wv * KC + c * 256 + lane * 4) = o;
      }
    }
    if (lane == 0) { ldss[8 + wv] = zl; ldss[24 + wv] = wamx; }
    __syncthreads();
    if (wv >= 8) {
      float* dst = ldsz + (wv - 8) * KC + lane * 4;
#pragma unroll
      for (int c = 0; c < 4; ++c) {
        float4 t = *reinterpret_cast<float4*>(dst + c * 256);
        t.x += zac[c*4+0]; t.y += zac[c*4+1]; t.z += zac[c*4+2]; t.w += zac[c*4+3];
        *reinterpret_cast<float4*>(dst + c * 256) = t;
      }
    }
    __syncthreads();
    {
      float s = 0.0f;
#pragma unroll
      for (int w = 0; w < 8; ++w) s += ldsz[w * KC + tid];
      AS(&zpart[(size_t)g * VSTR + tid], s);
    }
    if (tid == 0) {
      float zt = 0.0f;
#pragma unroll
      for (int w = 0; w < 16; ++w) zt += ldss[8 + w];
      AS(&zpart[(size_t)g * VSTR + KC], zt);
      float am = ldss[24];
#pragma unroll
      for (int w = 1; w < 16; ++w) am = fmaxf(am, ldss[24 + w]);
      __hip_atomic_fetch_max(ctrl + 320, __float_as_uint(am),
                             __ATOMIC_RELAXED, __HIP_MEMORY_SCOPE_AGENT);
    }
    ++seq; gbar(ctrl, flds, g, tid, seq, 0);

    // ---- P2: owned columns -> b (semi), replicated 8x ----
    if (tid < 256) {
      const float* zb = zpart + (size_t)tid * VSTR + g * CPB;
      const float z0 = AL(zb + 0), z1 = AL(zb + 1), z2 = AL(zb + 2), z3 = AL(zb + 3);
      const float s0 = wave_sum(z0), s1 = wave_sum(z1), s2 = wave_sum(z2), s3 = wave_sum(z3);
      float sl = 0.0f;
      if (g == NBLK - 1) sl = wave_sum(AL(zpart + (size_t)tid * VSTR + KC));
      if (lane == 0) {
        ldss[40 + wv * 4 + 0] = s0; ldss[40 + wv * 4 + 1] = s1;
        ldss[40 + wv * 4 + 2] = s2; ldss[40 + wv * 4 + 3] = s3;
        ldss[56 + wv] = sl;
      }
    }
    __syncthreads();
    if (tid == 0) {
      float bmx = -INFINITY;
#pragma unroll
      for (int c = 0; c < 4; ++c) {
        const float z    = ((ldss[40 + c] + ldss[44 + c]) + ldss[48 + c]) + ldss[52 + c];
        const float bnew = powf(PBJ / z, FI) * wlds[c];
#pragma unroll
        for (int rep = 0; rep < 8; ++rep) AS(&brep[rep * VSTR + g * CPB + c], bnew);
        bmx = fmaxf(bmx, bnew);
      }
      if (g == NBLK - 1) {
        const float z  = ((ldss[56] + ldss[57]) + ldss[58]) + ldss[59];
        const float bn = PBL / z;
#pragma unroll
        for (int rep = 0; rep < 8; ++rep) AS(&brep[rep * VSTR + KC], bn);
        bmx = fmaxf(bmx, bn);
      }
      __hip_atomic_fetch_max(ctrl + 320, __float_as_uint(bmx),
                             __ATOMIC_RELAXED, __HIP_MEMORY_SCOPE_AGENT);
    }
    ++seq;
    const unsigned fl = gbar(ctrl, flds, g, tid, seq, 1);
    stab = (int)(fl & 1u);
  }

  // ---------------- epilogue ----------------
  bstage[tid] = AL(&brep[rb + tid]);
  if (tid == 0) bstage[KC] = AL(&brep[rb + KC]);
  if (stab) {
    vstage[tid] = AL(&varr[vp * VSTR + tid]);
    if (tid == 0) vstage[KC] = AL(&varr[vp * VSTR + KC]);
  }
  __syncthreads();
  if (!stab) {
    float bf[16];
#pragma unroll
    for (int c = 0; c < 4; ++c) {
#pragma unroll
      for (int e = 0; e < 4; ++e) bf[c*4+e] = bstage[c * 256 + lane * 4 + e];
    }
#pragma unroll
    for (int r = 0; r < RPW; ++r) {
      const int lr = wv * RPW + r;
      const float ai = ra[lr];
      float* qr = Q + (size_t)(row0 + r) * KC + lane * 4;
#pragma unroll
      for (int c = 0; c < 4; ++c) {
        float4 t = *reinterpret_cast<const float4*>(qr + c * 256);
        t.x = ((ai * t.x) * bf[c*4+0]) * 16384.0f;
        t.y = ((ai * t.y) * bf[c*4+1]) * 16384.0f;
        t.z = ((ai * t.z) * bf[c*4+2]) * 16384.0f;
        t.w = ((ai * t.w) * bf[c*4+3]) * 16384.0f;
        *reinterpret_cast<float4*>(qr + c * 256) = t;
      }
    }
  } else {
    float v2f[16];
#pragma unroll
    for (int c = 0; c < 4; ++c) {
#pragma unroll
      for (int e = 0; e < 4; ++e) {
        const int j = c * 256 + lane * 4 + e;
        v2f[c*4+e] = vstage[j] + EPSF * logf(bstage[j] + TINY);
      }
    }
#pragma unroll
    for (int r = 0; r < RPW; ++r) {
      const int lr = wv * RPW + r;
      const float u2 = ru[lr] + EPSF * logf(ra[lr]);
      const float mi = rxm[lr], Li = rlr[lr];
      const float* xr = X + (size_t)(row0 + r) * KC + lane * 4;
      float* qr = Q + (size_t)(row0 + r) * KC + lane * 4;
#pragma unroll
      for (int c = 0; c < 4; ++c) {
        const float4 t = *reinterpret_cast<const float4*>(xr + c * 256);
        float4 o;
        o.x = expf((u2 - (Li - (t.x - mi)) + v2f[c*4+0]) / EPSF) * 16384.0f;
        o.y = expf((u2 - (Li - (t.y - mi)) + v2f[c*4+1]) / EPSF) * 16384.0f;
        o.z = expf((u2 - (Li - (t.z - mi)) + v2f[c*4+2]) / EPSF) * 16384.0f;
        o.w = expf((u2 - (Li - (t.w - mi)) + v2f[c*4+3]) / EPSF) * 16384.0f;
        *reinterpret_cast<float4*>(qr + c * 256) = o;
      }
    }
  }
}

extern "C" void kernel_launch(void* const* d_in, const int* in_sizes, int n_in,
                              void* d_out, int out_size, void* d_ws, size_t ws_size,
                              hipStream_t stream)
{
  (void)in_sizes; (void)n_in; (void)out_size; (void)ws_size;
  const float* X = (const float*)d_in[0];
  float* Q = (float*)d_out;
  hipMemsetAsync(d_ws, 0, 4096, stream);   // barrier counters, gmax, release flags
  void* args[3] = { (void*)&X, (void*)&Q, (void*)&d_ws };
  hipLaunchCooperativeKernel((const void*)sk_coop, dim3(NBLK), dim3(NTHR),
                             args, 0, stream);
}

// Round 5
// 22635.950 us; speedup vs baseline: 3.4290x; 1.2969x over previous
//
#include <hip/hip_runtime.h>
#include <math.h>

#define NROWS 16384
#define KC    1024
#define NBLK  256
#define NTHR  1024
#define WPB   16      // waves per block
#define RPW   4       // rows per wave; 64 rows per block
#define CPB   4       // regular columns owned per block (block 255 also owns col 1024)
#define VSTR  1056    // padded stride for (K+1)-length vectors
#define NITER 1000

// relaxed agent-scope (device-coherent) access
#define AL(p)    __hip_atomic_load((p), __ATOMIC_RELAXED, __HIP_MEMORY_SCOPE_AGENT)
#define AS(p,v)  __hip_atomic_store((p), (v), __ATOMIC_RELAXED, __HIP_MEMORY_SCOPE_AGENT)

__device__ __forceinline__ float wave_sum(float v) {
#pragma unroll
  for (int o = 32; o > 0; o >>= 1) v += __shfl_xor(v, o, 64);
  return v;
}
__device__ __forceinline__ float wave_max(float v) {
#pragma unroll
  for (int o = 32; o > 0; o >>= 1) v = fmaxf(v, __shfl_xor(v, o, 64));
  return v;
}

// bf16 pack/unpack (RNE), bit-exact cheap conversions
__device__ __forceinline__ unsigned short f2b(float f) {
  unsigned u = __float_as_uint(f);
  u += 0x7FFFu + ((u >> 16) & 1u);
  return (unsigned short)(u >> 16);
}
__device__ __forceinline__ float b2f(unsigned h) {
  return __uint_as_float(h << 16);
}
__device__ __forceinline__ void unpack8(const uint4 p, float* f) {
  f[0] = b2f(p.x & 0xffffu); f[1] = b2f(p.x >> 16);
  f[2] = b2f(p.y & 0xffffu); f[3] = b2f(p.y >> 16);
  f[4] = b2f(p.z & 0xffffu); f[5] = b2f(p.z >> 16);
  f[6] = b2f(p.w & 0xffffu); f[7] = b2f(p.w >> 16);
}
__device__ __forceinline__ uint4 pack8(const float* f) {
  uint4 p;
  p.x = (unsigned)f2b(f[0]) | ((unsigned)f2b(f[1]) << 16);
  p.y = (unsigned)f2b(f[2]) | ((unsigned)f2b(f[3]) << 16);
  p.z = (unsigned)f2b(f[4]) | ((unsigned)f2b(f[5]) << 16);
  p.w = (unsigned)f2b(f[6]) | ((unsigned)f2b(f[7]) << 16);
  return p;
}

// Fence-free two-level barrier over 256 blocks (round-3 verified).
// ctrl (uints): c1[8] at i*32, c2 at 288, gmax at 320, flags[8] at 352+i*32.
// Flag value = seq*2 | stab.
__device__ __forceinline__ unsigned gbar(unsigned* ctrl, unsigned* flds,
                                         int g, int tid, unsigned seq, int isb2) {
  __syncthreads();   // all waves' vmem (incl. coherent stores) drained before arrival
  if (tid == 0) {
    unsigned fl = 0;
    bool released = false;
    unsigned* c1 = ctrl + (((unsigned)g) >> 5) * 32;
    const unsigned o1 = __hip_atomic_fetch_add(c1, 1u, __ATOMIC_RELAXED, __HIP_MEMORY_SCOPE_AGENT);
    if (o1 == 31u) {
      AS(c1, 0u);
      asm volatile("s_waitcnt vmcnt(0)" ::: "memory");   // reset visible before signaling up
      unsigned* c2 = ctrl + 288;
      const unsigned o2 = __hip_atomic_fetch_add(c2, 1u, __ATOMIC_RELAXED, __HIP_MEMORY_SCOPE_AGENT);
      if (o2 == 7u) {
        unsigned stab = 0u;
        if (isb2) {
          const unsigned gm = AL(ctrl + 320);
          stab = (__uint_as_float(gm) > 1e8f) ? 1u : 0u;
          AS(ctrl + 320, 0u);
        }
        AS(c2, 0u);
        fl = seq * 2u + stab;
        asm volatile("s_waitcnt vmcnt(0)" ::: "memory"); // resets visible before release
#pragma unroll
        for (int i = 0; i < 8; ++i) AS(ctrl + 352 + i * 32, fl);
        flds[0] = fl;
        released = true;
      }
    }
    if (!released) {
      unsigned* myf = ctrl + 352 + (((unsigned)g) & 7u) * 32;
      for (;;) {
        fl = AL(myf);
        if (fl >= seq * 2u) break;
        __builtin_amdgcn_s_sleep(2);
      }
      flds[0] = fl;
    }
  }
  __syncthreads();
  return flds[0];
}

// Lane-column mapping: lane l owns cols [8l, 8l+8) and [512+8l, 512+8l+8).
__global__ __launch_bounds__(NTHR, 4)
void sk_coop(const float* __restrict__ X, void* __restrict__ Qv, void* __restrict__ wsv)
{
  const int g    = blockIdx.x;
  const int tid  = threadIdx.x;
  const int wv   = tid >> 6;
  const int lane = tid & 63;
  const int row0 = (g * WPB + wv) * RPW;
  const unsigned rb = (((unsigned)g) & 7u) * VSTR;

  unsigned short* Qh = (unsigned short*)Qv;   // bf16 Q, packed rows of KC
  float*          Qf = (float*)Qv;            // fp32 plan (epilogue)

  unsigned* ctrl = (unsigned*)wsv;
  float* varr  = (float*)((char*)wsv + 4096); // [2*VSTR] dual potentials (ping-pong)
  float* brep  = varr + 2 * VSTR;             // [8][VSTR] b replicas
  float* zpart = brep + 8 * VSTR;             // [NBLK][VSTR]

  __shared__ float ldsz[8 * KC];   // 32 KB z pair-reduce
  __shared__ float ldss[64];
  __shared__ float bstage[VSTR];
  __shared__ float vstage[VSTR];
  __shared__ float rq[64], rxm[64], rlr[64], ra[64], ru[64];  // per-row state
  __shared__ float wlds[CPB];
  __shared__ unsigned flds[1];

  const float FI   = (float)(1.0 / 1.1);
  const float FIM1 = (float)(1.0 / 1.1 - 1.0);
  const float TINY = 1.1920928955078125e-07f;
  const float PA   = 1.0f / 16384.0f;
  const float PBJ  = 0.5f / 1024.0f;
  const float PBL  = 0.5f;
  const float EPSF = 0.1f;

  // ---------------- init: softmax stats + Q0 in bf16 ----------------
  if (tid < CPB) {
    AS(&varr[g * CPB + tid], 0.0f);
    AS(&varr[VSTR + g * CPB + tid], 0.0f);
    wlds[tid] = 1.0f;
  }
  if (g == NBLK - 1 && tid == CPB) { AS(&varr[KC], 0.0f); AS(&varr[VSTR + KC], 0.0f); }
#pragma unroll
  for (int r = 0; r < RPW; ++r) {
    const int i  = row0 + r;
    const int lr = wv * RPW + r;
    const float* xr = X + (size_t)i * KC;
    float x[16];
    {
      const float4 t0 = *reinterpret_cast<const float4*>(xr + 8 * lane);
      const float4 t1 = *reinterpret_cast<const float4*>(xr + 8 * lane + 4);
      const float4 t2 = *reinterpret_cast<const float4*>(xr + 512 + 8 * lane);
      const float4 t3 = *reinterpret_cast<const float4*>(xr + 512 + 8 * lane + 4);
      x[0]=t0.x; x[1]=t0.y; x[2]=t0.z; x[3]=t0.w;
      x[4]=t1.x; x[5]=t1.y; x[6]=t1.z; x[7]=t1.w;
      x[8]=t2.x; x[9]=t2.y; x[10]=t2.z; x[11]=t2.w;
      x[12]=t3.x; x[13]=t3.y; x[14]=t3.z; x[15]=t3.w;
    }
    float mx = -INFINITY;
#pragma unroll
    for (int e = 0; e < 16; ++e) mx = fmaxf(mx, x[e]);
    mx = wave_max(mx);
    float s = 0.0f;
#pragma unroll
    for (int e = 0; e < 16; ++e) s += expf(x[e] - mx);
    s = wave_sum(s);
    const float L = logf(s);
    if (lane == 0) { rxm[lr] = mx; rlr[lr] = L; ru[lr] = 0.0f; rq[lr] = 1.0f; }
    float q[16];
#pragma unroll
    for (int e = 0; e < 16; ++e) q[e] = expf(((x[e] - mx) - L) / EPSF);
    uint4* qrow = (uint4*)(Qh + (size_t)i * KC);
    qrow[lane]      = pack8(q);
    qrow[64 + lane] = pack8(q + 8);
  }
  // no global sync needed before iter 0: b(0) is constant, Q rows are wave-local

  // ---------------- main loop ----------------
  int vp = 0, stab = 0;
  unsigned seq = 0;

  for (int it = 0; it < NITER; ++it) {
    // ---- stage b into LDS ----
    if (it == 0) {
      bstage[tid] = 1.0f / 1025.0f;
      if (tid == 0) bstage[KC] = 1.0f / 1025.0f;
    } else {
      bstage[tid] = AL(&brep[rb + tid]);
      if (tid == 0) bstage[KC] = AL(&brep[rb + KC]);
    }

    float zac[16];
#pragma unroll
    for (int e = 0; e < 16; ++e) zac[e] = 0.0f;
    float zl = 0.0f, amx = -INFINITY;

    if (!stab) {
      // ---- P1 normal: y = Q b ; a = Pa/y ; z += a_i * Q_i ----
      uint4 qb[RPW][2];
      const uint4* qr0 = (const uint4*)(Qh + (size_t)row0 * KC);
#pragma unroll
      for (int r = 0; r < RPW; ++r) {
        qb[r][0] = qr0[r * 128 + lane];
        qb[r][1] = qr0[r * 128 + 64 + lane];
      }
      __syncthreads();          // bstage ready
      float bf[16];
      {
        const float4 t0 = *reinterpret_cast<const float4*>(&bstage[8 * lane]);
        const float4 t1 = *reinterpret_cast<const float4*>(&bstage[8 * lane + 4]);
        const float4 t2 = *reinterpret_cast<const float4*>(&bstage[512 + 8 * lane]);
        const float4 t3 = *reinterpret_cast<const float4*>(&bstage[512 + 8 * lane + 4]);
        bf[0]=t0.x; bf[1]=t0.y; bf[2]=t0.z; bf[3]=t0.w;
        bf[4]=t1.x; bf[5]=t1.y; bf[6]=t1.z; bf[7]=t1.w;
        bf[8]=t2.x; bf[9]=t2.y; bf[10]=t2.z; bf[11]=t2.w;
        bf[12]=t3.x; bf[13]=t3.y; bf[14]=t3.z; bf[15]=t3.w;
      }
      const float bl = bstage[KC];
#pragma unroll
      for (int r = 0; r < RPW; ++r) {
        const int lr = wv * RPW + r;
        float q[16];
        unpack8(qb[r][0], q);
        unpack8(qb[r][1], q + 8);
        float d = 0.0f;
#pragma unroll
        for (int e = 0; e < 16; ++e) d = fmaf(q[e], bf[e], d);
        const float ql = rq[lr];
        const float y  = wave_sum(d) + ql * bl;
        const float ai = PA / y;
        if (lane == 0) ra[lr] = ai;
        amx = fmaxf(amx, ai);
#pragma unroll
        for (int e = 0; e < 16; ++e) zac[e] = fmaf(ai, q[e], zac[e]);
        zl = fmaf(ai, ql, zl);
      }
    } else {
      // ---- P1 deferred stabilization: rewrite Q from logits; b := ones ----
      vstage[tid] = AL(&varr[vp * VSTR + tid]);
      if (tid == 0) vstage[KC] = AL(&varr[vp * VSTR + KC]);
      __syncthreads();
      if (tid < CPB) {
        const int j = g * CPB + tid;
        const float bj = bstage[j];
        AS(&varr[(vp ^ 1) * VSTR + j], vstage[j] + EPSF * logf(bj + TINY));
        wlds[tid] = wlds[tid] * powf(bj, FIM1);
      }
      if (g == NBLK - 1 && tid == CPB)
        AS(&varr[(vp ^ 1) * VSTR + KC], vstage[KC] + EPSF * logf(bstage[KC] + TINY));
      float v2f[16];
#pragma unroll
      for (int e = 0; e < 16; ++e) {
        const int j = (e < 8) ? (8 * lane + e) : (512 + 8 * lane + (e - 8));
        v2f[e] = vstage[j] + EPSF * logf(bstage[j] + TINY);
      }
      const float v2l = vstage[KC] + EPSF * logf(bstage[KC] + TINY);
#pragma unroll
      for (int r = 0; r < RPW; ++r) {
        const int i  = row0 + r;
        const int lr = wv * RPW + r;
        const float u2 = ru[lr] + EPSF * logf(ra[lr]);
        if (lane == 0) ru[lr] = u2;
        const float mi = rxm[lr], Li = rlr[lr];
        const float* xr = X + (size_t)i * KC;
        float q[16];
        {
          const float4 t0 = *reinterpret_cast<const float4*>(xr + 8 * lane);
          const float4 t1 = *reinterpret_cast<const float4*>(xr + 8 * lane + 4);
          const float4 t2 = *reinterpret_cast<const float4*>(xr + 512 + 8 * lane);
          const float4 t3 = *reinterpret_cast<const float4*>(xr + 512 + 8 * lane + 4);
          q[0]=t0.x; q[1]=t0.y; q[2]=t0.z; q[3]=t0.w;
          q[4]=t1.x; q[5]=t1.y; q[6]=t1.z; q[7]=t1.w;
          q[8]=t2.x; q[9]=t2.y; q[10]=t2.z; q[11]=t2.w;
          q[12]=t3.x; q[13]=t3.y; q[14]=t3.z; q[15]=t3.w;
        }
#pragma unroll
        for (int e = 0; e < 16; ++e) {
          const float cost = Li - (q[e] - mi);
          q[e] = expf((u2 - cost + v2f[e]) / EPSF);
        }
        uint4* qrow = (uint4*)(Qh + (size_t)i * KC);
        qrow[lane]      = pack8(q);
        qrow[64 + lane] = pack8(q + 8);
        float d = 0.0f;
#pragma unroll
        for (int e = 0; e < 16; ++e) d += q[e];
        const float ql = expf((u2 + v2l) / EPSF);
        if (lane == 0) rq[lr] = ql;
        const float y  = wave_sum(d) + ql;
        const float ai = PA / y;
        if (lane == 0) ra[lr] = ai;
        amx = fmaxf(amx, ai);
#pragma unroll
        for (int e = 0; e < 16; ++e) zac[e] = fmaf(ai, q[e], zac[e]);
        zl = fmaf(ai, ql, zl);
      }
      vp ^= 1;
    }

    // ---- z reduce: 16 waves -> 8 LDS rows -> 1 zpart row ----
    const float wamx = wave_max(amx);
    __syncthreads();
    if (wv < 8) {
      float* dst = ldsz + wv * KC;
      *reinterpret_cast<float4*>(&dst[8 * lane])           = make_float4(zac[0], zac[1], zac[2], zac[3]);
      *reinterpret_cast<float4*>(&dst[8 * lane + 4])       = make_float4(zac[4], zac[5], zac[6], zac[7]);
      *reinterpret_cast<float4*>(&dst[512 + 8 * lane])     = make_float4(zac[8], zac[9], zac[10], zac[11]);
      *reinterpret_cast<float4*>(&dst[512 + 8 * lane + 4]) = make_float4(zac[12], zac[13], zac[14], zac[15]);
    }
    if (lane == 0) { ldss[8 + wv] = zl; ldss[24 + wv] = wamx; }
    __syncthreads();
    if (wv >= 8) {
      float* dst = ldsz + (wv - 8) * KC;
      float4 t;
      t = *reinterpret_cast<float4*>(&dst[8 * lane]);
      t.x += zac[0]; t.y += zac[1]; t.z += zac[2]; t.w += zac[3];
      *reinterpret_cast<float4*>(&dst[8 * lane]) = t;
      t = *reinterpret_cast<float4*>(&dst[8 * lane + 4]);
      t.x += zac[4]; t.y += zac[5]; t.z += zac[6]; t.w += zac[7];
      *reinterpret_cast<float4*>(&dst[8 * lane + 4]) = t;
      t = *reinterpret_cast<float4*>(&dst[512 + 8 * lane]);
      t.x += zac[8]; t.y += zac[9]; t.z += zac[10]; t.w += zac[11];
      *reinterpret_cast<float4*>(&dst[512 + 8 * lane]) = t;
      t = *reinterpret_cast<float4*>(&dst[512 + 8 * lane + 4]);
      t.x += zac[12]; t.y += zac[13]; t.z += zac[14]; t.w += zac[15];
      *reinterpret_cast<float4*>(&dst[512 + 8 * lane + 4]) = t;
    }
    __syncthreads();
    {
      float s = 0.0f;
#pragma unroll
      for (int w = 0; w < 8; ++w) s += ldsz[w * KC + tid];
      AS(&zpart[(size_t)g * VSTR + tid], s);
    }
    if (tid == 0) {
      float zt = 0.0f;
#pragma unroll
      for (int w = 0; w < 16; ++w) zt += ldss[8 + w];
      AS(&zpart[(size_t)g * VSTR + KC], zt);
      float am = ldss[24];
#pragma unroll
      for (int w = 1; w < 16; ++w) am = fmaxf(am, ldss[24 + w]);
      __hip_atomic_fetch_max(ctrl + 320, __float_as_uint(am),
                             __ATOMIC_RELAXED, __HIP_MEMORY_SCOPE_AGENT);
    }
    ++seq; gbar(ctrl, flds, g, tid, seq, 0);

    // ---- P2: owned columns -> b (semi), replicated 8x ----
    if (tid < 256) {
      const float* zb = zpart + (size_t)tid * VSTR + g * CPB;
      const float z0 = AL(zb + 0), z1 = AL(zb + 1), z2 = AL(zb + 2), z3 = AL(zb + 3);
      const float s0 = wave_sum(z0), s1 = wave_sum(z1), s2 = wave_sum(z2), s3 = wave_sum(z3);
      float sl = 0.0f;
      if (g == NBLK - 1) sl = wave_sum(AL(zpart + (size_t)tid * VSTR + KC));
      if (lane == 0) {
        ldss[40 + wv * 4 + 0] = s0; ldss[40 + wv * 4 + 1] = s1;
        ldss[40 + wv * 4 + 2] = s2; ldss[40 + wv * 4 + 3] = s3;
        ldss[56 + wv] = sl;
      }
    }
    __syncthreads();
    if (tid == 0) {
      float bmx = -INFINITY;
#pragma unroll
      for (int c = 0; c < CPB; ++c) {
        const float z    = ((ldss[40 + c] + ldss[44 + c]) + ldss[48 + c]) + ldss[52 + c];
        const float bnew = powf(PBJ / z, FI) * wlds[c];
#pragma unroll
        for (int rep = 0; rep < 8; ++rep) AS(&brep[rep * VSTR + g * CPB + c], bnew);
        bmx = fmaxf(bmx, bnew);
      }
      if (g == NBLK - 1) {
        const float z  = ((ldss[56] + ldss[57]) + ldss[58]) + ldss[59];
        const float bn = PBL / z;
#pragma unroll
        for (int rep = 0; rep < 8; ++rep) AS(&brep[rep * VSTR + KC], bn);
        bmx = fmaxf(bmx, bn);
      }
      __hip_atomic_fetch_max(ctrl + 320, __float_as_uint(bmx),
                             __ATOMIC_RELAXED, __HIP_MEMORY_SCOPE_AGENT);
    }
    ++seq;
    const unsigned fl = gbar(ctrl, flds, g, tid, seq, 1);
    stab = (int)(fl & 1u);
  }

  // ---------------- epilogue ----------------
  bstage[tid] = AL(&brep[rb + tid]);
  if (tid == 0) bstage[KC] = AL(&brep[rb + KC]);
  if (stab) {
    vstage[tid] = AL(&varr[vp * VSTR + tid]);
    if (tid == 0) vstage[KC] = AL(&varr[vp * VSTR + KC]);
  }
  __syncthreads();

  if (!stab) {
    // plan = n * a_i * Qbf16_ij * b_j, expanded bf16->fp32 in place.
    // Geometric phases: fp32 rows [lo,2lo) clobber bf16 rows [2lo,4lo),
    // which were consumed in the previous phase.
    float bf[16];
    {
      const float4 t0 = *reinterpret_cast<const float4*>(&bstage[8 * lane]);
      const float4 t1 = *reinterpret_cast<const float4*>(&bstage[8 * lane + 4]);
      const float4 t2 = *reinterpret_cast<const float4*>(&bstage[512 + 8 * lane]);
      const float4 t3 = *reinterpret_cast<const float4*>(&bstage[512 + 8 * lane + 4]);
      bf[0]=t0.x; bf[1]=t0.y; bf[2]=t0.z; bf[3]=t0.w;
      bf[4]=t1.x; bf[5]=t1.y; bf[6]=t1.z; bf[7]=t1.w;
      bf[8]=t2.x; bf[9]=t2.y; bf[10]=t2.z; bf[11]=t2.w;
      bf[12]=t3.x; bf[13]=t3.y; bf[14]=t3.z; bf[15]=t3.w;
    }
    for (int ph = 0; ph < 8; ++ph) {
      const int lo = 8192 >> ph, hi = 16384 >> ph;
      if (row0 >= lo && row0 < hi) {
#pragma unroll
        for (int r = 0; r < RPW; ++r) {
          const int i  = row0 + r;
          const int lr = wv * RPW + r;
          const float an = ra[lr] * 16384.0f;
          const uint4* qrow = (const uint4*)(Qh + (size_t)i * KC);
          const uint4 p0 = qrow[lane], p1 = qrow[64 + lane];
          float q[16];
          unpack8(p0, q); unpack8(p1, q + 8);
          float* orow = Qf + (size_t)i * KC;
          *reinterpret_cast<float4*>(orow + 8 * lane) =
            make_float4(an*q[0]*bf[0], an*q[1]*bf[1], an*q[2]*bf[2], an*q[3]*bf[3]);
          *reinterpret_cast<float4*>(orow + 8 * lane + 4) =
            make_float4(an*q[4]*bf[4], an*q[5]*bf[5], an*q[6]*bf[6], an*q[7]*bf[7]);
          *reinterpret_cast<float4*>(orow + 512 + 8 * lane) =
            make_float4(an*q[8]*bf[8], an*q[9]*bf[9], an*q[10]*bf[10], an*q[11]*bf[11]);
          *reinterpret_cast<float4*>(orow + 512 + 8 * lane + 4) =
            make_float4(an*q[12]*bf[12], an*q[13]*bf[13], an*q[14]*bf[14], an*q[15]*bf[15]);
        }
      }
      ++seq; gbar(ctrl, flds, g, tid, seq, 0);
    }
    // rows [0,64): block 0 stages all its bf16 rows to registers first
    if (g == 0) {
      uint4 s8[RPW][2];
#pragma unroll
      for (int r = 0; r < RPW; ++r) {
        const uint4* qrow = (const uint4*)(Qh + (size_t)(row0 + r) * KC);
        s8[r][0] = qrow[lane];
        s8[r][1] = qrow[64 + lane];
      }
      __syncthreads();   // drains loads (vmcnt) before any fp32 store
#pragma unroll
      for (int r = 0; r < RPW; ++r) {
        const int i  = row0 + r;
        const int lr = wv * RPW + r;
        const float an = ra[lr] * 16384.0f;
        float q[16];
        unpack8(s8[r][0], q); unpack8(s8[r][1], q + 8);
        float* orow = Qf + (size_t)i * KC;
        *reinterpret_cast<float4*>(orow + 8 * lane) =
          make_float4(an*q[0]*bf[0], an*q[1]*bf[1], an*q[2]*bf[2], an*q[3]*bf[3]);
        *reinterpret_cast<float4*>(orow + 8 * lane + 4) =
          make_float4(an*q[4]*bf[4], an*q[5]*bf[5], an*q[6]*bf[6], an*q[7]*bf[7]);
        *reinterpret_cast<float4*>(orow + 512 + 8 * lane) =
          make_float4(an*q[8]*bf[8], an*q[9]*bf[9], an*q[10]*bf[10], an*q[11]*bf[11]);
        *reinterpret_cast<float4*>(orow + 512 + 8 * lane + 4) =
          make_float4(an*q[12]*bf[12], an*q[13]*bf[13], an*q[14]*bf[14], an*q[15]*bf[15]);
      }
    }
  } else {
    // pending stabilization at exit: plan = n * exp((u2 - cost + v2^T)/eps), from X
    float v2f[16];
#pragma unroll
    for (int e = 0; e < 16; ++e) {
      const int j = (e < 8) ? (8 * lane + e) : (512 + 8 * lane + (e - 8));
      v2f[e] = vstage[j] + EPSF * logf(bstage[j] + TINY);
    }
#pragma unroll
    for (int r = 0; r < RPW; ++r) {
      const int i  = row0 + r;
      const int lr = wv * RPW + r;
      const float u2 = ru[lr] + EPSF * logf(ra[lr]);
      const float mi = rxm[lr], Li = rlr[lr];
      const float* xr = X + (size_t)i * KC;
      float x[16];
      {
        const float4 t0 = *reinterpret_cast<const float4*>(xr + 8 * lane);
        const float4 t1 = *reinterpret_cast<const float4*>(xr + 8 * lane + 4);
        const float4 t2 = *reinterpret_cast<const float4*>(xr + 512 + 8 * lane);
        const float4 t3 = *reinterpret_cast<const float4*>(xr + 512 + 8 * lane + 4);
        x[0]=t0.x; x[1]=t0.y; x[2]=t0.z; x[3]=t0.w;
        x[4]=t1.x; x[5]=t1.y; x[6]=t1.z; x[7]=t1.w;
        x[8]=t2.x; x[9]=t2.y; x[10]=t2.z; x[11]=t2.w;
        x[12]=t3.x; x[13]=t3.y; x[14]=t3.z; x[15]=t3.w;
      }
      float q[16];
#pragma unroll
      for (int e = 0; e < 16; ++e)
        q[e] = expf((u2 - (Li - (x[e] - mi)) + v2f[e]) / EPSF) * 16384.0f;
      float* orow = Qf + (size_t)i * KC;
      *reinterpret_cast<float4*>(orow + 8 * lane)           = make_float4(q[0], q[1], q[2], q[3]);
      *reinterpret_cast<float4*>(orow + 8 * lane + 4)       = make_float4(q[4], q[5], q[6], q[7]);
      *reinterpret_cast<float4*>(orow + 512 + 8 * lane)     = make_float4(q[8], q[9], q[10], q[11]);
      *reinterpret_cast<float4*>(orow + 512 + 8 * lane + 4) = make_float4(q[12], q[13], q[14], q[15]);
    }
  }
}

extern "C" void kernel_launch(void* const* d_in, const int* in_sizes, int n_in,
                              void* d_out, int out_size, void* d_ws, size_t ws_size,
                              hipStream_t stream)
{
  (void)in_sizes; (void)n_in; (void)out_size; (void)ws_size;
  const float* X = (const float*)d_in[0];
  hipMemsetAsync(d_ws, 0, 4096, stream);   // barrier counters, gmax, release flags
  void* args[3] = { (void*)&X, (void*)&d_out, (void*)&d_ws };
  hipLaunchCooperativeKernel((const void*)sk_coop, dim3(NBLK), dim3(NTHR),
                             args, 0, stream);
}

// Round 6
// 17449.821 us; speedup vs baseline: 4.4480x; 1.2972x over previous
//
#include <hip/hip_runtime.h>
#include <math.h>

#define NROWS 16384
#define KC    1024
#define NBLK  256
#define NTHR  1024
#define WPB   16      // waves per block
#define RPW   4       // rows per wave; 64 rows per block
#define CPB   4       // regular columns owned per block (block 255 also owns col 1024)
#define VSTR  1056    // padded stride for (K+1)-length vectors
#define NITER 1000

// relaxed agent-scope (device-coherent) access
#define AL(p)    __hip_atomic_load((p), __ATOMIC_RELAXED, __HIP_MEMORY_SCOPE_AGENT)
#define AS(p,v)  __hip_atomic_store((p), (v), __ATOMIC_RELAXED, __HIP_MEMORY_SCOPE_AGENT)

__device__ __forceinline__ float wave_sum(float v) {
#pragma unroll
  for (int o = 32; o > 0; o >>= 1) v += __shfl_xor(v, o, 64);
  return v;
}
__device__ __forceinline__ float wave_max(float v) {
#pragma unroll
  for (int o = 32; o > 0; o >>= 1) v = fmaxf(v, __shfl_xor(v, o, 64));
  return v;
}

// bf16 pack/unpack (RNE)
__device__ __forceinline__ unsigned short f2b(float f) {
  unsigned u = __float_as_uint(f);
  u += 0x7FFFu + ((u >> 16) & 1u);
  return (unsigned short)(u >> 16);
}
__device__ __forceinline__ float b2f(unsigned h) {
  return __uint_as_float(h << 16);
}
__device__ __forceinline__ void unpack8(const uint4 p, float* f) {
  f[0] = b2f(p.x & 0xffffu); f[1] = b2f(p.x >> 16);
  f[2] = b2f(p.y & 0xffffu); f[3] = b2f(p.y >> 16);
  f[4] = b2f(p.z & 0xffffu); f[5] = b2f(p.z >> 16);
  f[6] = b2f(p.w & 0xffffu); f[7] = b2f(p.w >> 16);
}
__device__ __forceinline__ uint4 pack8(const float* f) {
  uint4 p;
  p.x = (unsigned)f2b(f[0]) | ((unsigned)f2b(f[1]) << 16);
  p.y = (unsigned)f2b(f[2]) | ((unsigned)f2b(f[3]) << 16);
  p.z = (unsigned)f2b(f[4]) | ((unsigned)f2b(f[5]) << 16);
  p.w = (unsigned)f2b(f[6]) | ((unsigned)f2b(f[7]) << 16);
  return p;
}

// Fence-free two-level barrier over 256 blocks (round-3/5 verified).
// ctrl (uints): c1[8] at i*32, c2 at 288, gmax at 320, flags[8] at 352+i*32.
// Flag value = seq*2 | stab.
__device__ __forceinline__ unsigned gbar(unsigned* ctrl, unsigned* flds,
                                         int g, int tid, unsigned seq, int isb2) {
  __syncthreads();   // all waves' vmem (incl. coherent stores) drained before arrival
  if (tid == 0) {
    unsigned fl = 0;
    bool released = false;
    unsigned* c1 = ctrl + (((unsigned)g) >> 5) * 32;
    const unsigned o1 = __hip_atomic_fetch_add(c1, 1u, __ATOMIC_RELAXED, __HIP_MEMORY_SCOPE_AGENT);
    if (o1 == 31u) {
      AS(c1, 0u);
      asm volatile("s_waitcnt vmcnt(0)" ::: "memory");   // reset visible before signaling up
      unsigned* c2 = ctrl + 288;
      const unsigned o2 = __hip_atomic_fetch_add(c2, 1u, __ATOMIC_RELAXED, __HIP_MEMORY_SCOPE_AGENT);
      if (o2 == 7u) {
        unsigned stab = 0u;
        if (isb2) {
          const unsigned gm = AL(ctrl + 320);
          stab = (__uint_as_float(gm) > 1e8f) ? 1u : 0u;
          AS(ctrl + 320, 0u);
        }
        AS(c2, 0u);
        fl = seq * 2u + stab;
        asm volatile("s_waitcnt vmcnt(0)" ::: "memory"); // resets visible before release
#pragma unroll
        for (int i = 0; i < 8; ++i) AS(ctrl + 352 + i * 32, fl);
        flds[0] = fl;
        released = true;
      }
    }
    if (!released) {
      unsigned* myf = ctrl + 352 + (((unsigned)g) & 7u) * 32;
      for (;;) {
        fl = AL(myf);
        if (fl >= seq * 2u) break;
        __builtin_amdgcn_s_sleep(2);
      }
      flds[0] = fl;
    }
  }
  __syncthreads();
  return flds[0];
}

// Lane-column mapping: lane l owns cols [8l, 8l+8) and [512+8l, 512+8l+8).
// zred row layout (1024 floats): chunk k (0..3) at [k*256 + lane*4 .. +3]:
//   k=0: cols 8l..8l+3, k=1: 8l+4..8l+7, k=2: 512+8l..+3, k=3: 512+8l+4..+7
__global__ __launch_bounds__(NTHR, 4)
void sk_coop(const float* __restrict__ X, float* __restrict__ Qf, void* __restrict__ wsv)
{
  const int g    = blockIdx.x;
  const int tid  = threadIdx.x;
  const int wv   = tid >> 6;
  const int lane = tid & 63;
  const int row0 = (g * WPB + wv) * RPW;   // global row base for this wave
  const unsigned rb = (((unsigned)g) & 7u) * VSTR;

  unsigned* ctrl = (unsigned*)wsv;
  float* varr  = (float*)((char*)wsv + 4096); // [2*VSTR] dual potentials (ping-pong)
  float* brep  = varr + 2 * VSTR;             // [8][VSTR] b replicas
  float* zpart = brep + 8 * VSTR;             // [NBLK][VSTR]

  // ---- LDS: whole Q tile resident across the loop (131 KB) ----
  __shared__ unsigned short Qs[64 * KC];      // bf16, row lr at Qs + lr*KC
  __shared__ float zred[4 * KC];              // 16 KB z accumulate (4 rows)
  __shared__ float bstage[VSTR];
  __shared__ float rq[64], rxm[64], rlr[64], ra[64], ru[64];  // per-local-row state
  __shared__ float wlds[CPB];
  __shared__ float ldss[64];
  __shared__ unsigned flds[1];

  const float FI   = (float)(1.0 / 1.1);
  const float FIM1 = (float)(1.0 / 1.1 - 1.0);
  const float TINY = 1.1920928955078125e-07f;
  const float PA   = 1.0f / 16384.0f;
  const float PBJ  = 0.5f / 1024.0f;
  const float PBL  = 0.5f;
  const float EPSF = 0.1f;

  // ---------------- init: softmax stats + Q0 (bf16) into LDS ----------------
  if (tid < CPB) {
    AS(&varr[g * CPB + tid], 0.0f);
    AS(&varr[VSTR + g * CPB + tid], 0.0f);
    wlds[tid] = 1.0f;
  }
  if (g == NBLK - 1 && tid == CPB) { AS(&varr[KC], 0.0f); AS(&varr[VSTR + KC], 0.0f); }
#pragma unroll
  for (int r = 0; r < RPW; ++r) {
    const int i  = row0 + r;
    const int lr = wv * RPW + r;
    const float* xr = X + (size_t)i * KC;
    float x[16];
    {
      const float4 t0 = *reinterpret_cast<const float4*>(xr + 8 * lane);
      const float4 t1 = *reinterpret_cast<const float4*>(xr + 8 * lane + 4);
      const float4 t2 = *reinterpret_cast<const float4*>(xr + 512 + 8 * lane);
      const float4 t3 = *reinterpret_cast<const float4*>(xr + 512 + 8 * lane + 4);
      x[0]=t0.x; x[1]=t0.y; x[2]=t0.z; x[3]=t0.w;
      x[4]=t1.x; x[5]=t1.y; x[6]=t1.z; x[7]=t1.w;
      x[8]=t2.x; x[9]=t2.y; x[10]=t2.z; x[11]=t2.w;
      x[12]=t3.x; x[13]=t3.y; x[14]=t3.z; x[15]=t3.w;
    }
    float mx = -INFINITY;
#pragma unroll
    for (int e = 0; e < 16; ++e) mx = fmaxf(mx, x[e]);
    mx = wave_max(mx);
    float s = 0.0f;
#pragma unroll
    for (int e = 0; e < 16; ++e) s += expf(x[e] - mx);
    s = wave_sum(s);
    const float L = logf(s);
    if (lane == 0) { rxm[lr] = mx; rlr[lr] = L; ru[lr] = 0.0f; rq[lr] = 1.0f; }
    float q[16];
#pragma unroll
    for (int e = 0; e < 16; ++e) q[e] = expf(((x[e] - mx) - L) / EPSF);
    uint4* qrow = (uint4*)(Qs + (size_t)lr * KC);
    qrow[lane]      = pack8(q);
    qrow[64 + lane] = pack8(q + 8);
  }
  // no global sync needed before iter 0: b(0) is constant, Q rows are wave-local

  // ---------------- main loop ----------------
  int vp = 0, stab = 0;
  unsigned seq = 0;

  for (int it = 0; it < NITER; ++it) {
    // ---- stage b into LDS ----
    if (it == 0) {
      bstage[tid] = 1.0f / 1025.0f;
      if (tid == 0) bstage[KC] = 1.0f / 1025.0f;
    } else {
      bstage[tid] = AL(&brep[rb + tid]);
      if (tid == 0) bstage[KC] = AL(&brep[rb + KC]);
    }
    __syncthreads();

    float zac[16];
#pragma unroll
    for (int e = 0; e < 16; ++e) zac[e] = 0.0f;
    float zl = 0.0f, amx = -INFINITY;

    float bf[16];
    {
      const float4 t0 = *reinterpret_cast<const float4*>(&bstage[8 * lane]);
      const float4 t1 = *reinterpret_cast<const float4*>(&bstage[8 * lane + 4]);
      const float4 t2 = *reinterpret_cast<const float4*>(&bstage[512 + 8 * lane]);
      const float4 t3 = *reinterpret_cast<const float4*>(&bstage[512 + 8 * lane + 4]);
      bf[0]=t0.x; bf[1]=t0.y; bf[2]=t0.z; bf[3]=t0.w;
      bf[4]=t1.x; bf[5]=t1.y; bf[6]=t1.z; bf[7]=t1.w;
      bf[8]=t2.x; bf[9]=t2.y; bf[10]=t2.z; bf[11]=t2.w;
      bf[12]=t3.x; bf[13]=t3.y; bf[14]=t3.z; bf[15]=t3.w;
    }
    const float bl = bstage[KC];

    if (!stab) {
      // ---- P1 from LDS: y = Q b ; a = Pa/y ; z += a_i * Q_i ----
#pragma unroll
      for (int r = 0; r < RPW; ++r) {
        const int lr = wv * RPW + r;
        const uint4* qrow = (const uint4*)(Qs + (size_t)lr * KC);
        const uint4 p0 = qrow[lane], p1 = qrow[64 + lane];
        float q[16];
        unpack8(p0, q); unpack8(p1, q + 8);
        float d = 0.0f;
#pragma unroll
        for (int e = 0; e < 16; ++e) d = fmaf(q[e], bf[e], d);
        const float ql = rq[lr];
        const float y  = wave_sum(d) + ql * bl;
        const float ai = PA / y;
        if (lane == 0) ra[lr] = ai;
        amx = fmaxf(amx, ai);
#pragma unroll
        for (int e = 0; e < 16; ++e) zac[e] = fmaf(ai, q[e], zac[e]);
        zl = fmaf(ai, ql, zl);
      }
    } else {
      // ---- P1 deferred stabilization: rewrite Q (LDS) from logits; b := ones ----
      if (tid < CPB) {
        const int j = g * CPB + tid;
        const float bj = bstage[j];
        AS(&varr[(vp ^ 1) * VSTR + j], AL(&varr[vp * VSTR + j]) + EPSF * logf(bj + TINY));
        wlds[tid] = wlds[tid] * powf(bj, FIM1);
      }
      if (g == NBLK - 1 && tid == CPB)
        AS(&varr[(vp ^ 1) * VSTR + KC], AL(&varr[vp * VSTR + KC]) + EPSF * logf(bstage[KC] + TINY));
      float v2f[16];
#pragma unroll
      for (int e = 0; e < 16; ++e) {
        const int j = (e < 8) ? (8 * lane + e) : (512 + 8 * lane + (e - 8));
        v2f[e] = AL(&varr[vp * VSTR + j]) + EPSF * logf(bstage[j] + TINY);
      }
      const float v2l = AL(&varr[vp * VSTR + KC]) + EPSF * logf(bstage[KC] + TINY);
#pragma unroll
      for (int r = 0; r < RPW; ++r) {
        const int i  = row0 + r;
        const int lr = wv * RPW + r;
        const float u2 = ru[lr] + EPSF * logf(ra[lr]);
        if (lane == 0) ru[lr] = u2;
        const float mi = rxm[lr], Li = rlr[lr];
        const float* xr = X + (size_t)i * KC;
        float q[16];
        {
          const float4 t0 = *reinterpret_cast<const float4*>(xr + 8 * lane);
          const float4 t1 = *reinterpret_cast<const float4*>(xr + 8 * lane + 4);
          const float4 t2 = *reinterpret_cast<const float4*>(xr + 512 + 8 * lane);
          const float4 t3 = *reinterpret_cast<const float4*>(xr + 512 + 8 * lane + 4);
          q[0]=t0.x; q[1]=t0.y; q[2]=t0.z; q[3]=t0.w;
          q[4]=t1.x; q[5]=t1.y; q[6]=t1.z; q[7]=t1.w;
          q[8]=t2.x; q[9]=t2.y; q[10]=t2.z; q[11]=t2.w;
          q[12]=t3.x; q[13]=t3.y; q[14]=t3.z; q[15]=t3.w;
        }
#pragma unroll
        for (int e = 0; e < 16; ++e) {
          const float cost = Li - (q[e] - mi);
          q[e] = expf((u2 - cost + v2f[e]) / EPSF);
        }
        uint4* qrow = (uint4*)(Qs + (size_t)lr * KC);
        qrow[lane]      = pack8(q);
        qrow[64 + lane] = pack8(q + 8);
        float d = 0.0f;
#pragma unroll
        for (int e = 0; e < 16; ++e) d += q[e];
        const float ql = expf((u2 + v2l) / EPSF);
        if (lane == 0) rq[lr] = ql;
        const float y  = wave_sum(d) + ql;
        const float ai = PA / y;
        if (lane == 0) ra[lr] = ai;
        amx = fmaxf(amx, ai);
#pragma unroll
        for (int e = 0; e < 16; ++e) zac[e] = fmaf(ai, q[e], zac[e]);
        zl = fmaf(ai, ql, zl);
      }
      vp ^= 1;
    }

    // ---- z reduce: 4-phase accumulate into zred[4][KC] (conflict-free layout) ----
    const float wamx = wave_max(amx);
    if (lane == 0) { ldss[wv] = zl; ldss[16 + wv] = wamx; }
    float* zrow = zred + (wv & 3) * KC;
    const int gp = wv >> 2;
    __syncthreads();
    if (gp == 0) {
      *reinterpret_cast<float4*>(&zrow[lane * 4])       = make_float4(zac[0], zac[1], zac[2], zac[3]);
      *reinterpret_cast<float4*>(&zrow[256 + lane * 4]) = make_float4(zac[4], zac[5], zac[6], zac[7]);
      *reinterpret_cast<float4*>(&zrow[512 + lane * 4]) = make_float4(zac[8], zac[9], zac[10], zac[11]);
      *reinterpret_cast<float4*>(&zrow[768 + lane * 4]) = make_float4(zac[12], zac[13], zac[14], zac[15]);
    }
    __syncthreads();
#pragma unroll
    for (int p = 1; p < 4; ++p) {
      if (gp == p) {
        float4 t;
        t = *reinterpret_cast<float4*>(&zrow[lane * 4]);
        t.x += zac[0]; t.y += zac[1]; t.z += zac[2]; t.w += zac[3];
        *reinterpret_cast<float4*>(&zrow[lane * 4]) = t;
        t = *reinterpret_cast<float4*>(&zrow[256 + lane * 4]);
        t.x += zac[4]; t.y += zac[5]; t.z += zac[6]; t.w += zac[7];
        *reinterpret_cast<float4*>(&zrow[256 + lane * 4]) = t;
        t = *reinterpret_cast<float4*>(&zrow[512 + lane * 4]);
        t.x += zac[8]; t.y += zac[9]; t.z += zac[10]; t.w += zac[11];
        *reinterpret_cast<float4*>(&zrow[512 + lane * 4]) = t;
        t = *reinterpret_cast<float4*>(&zrow[768 + lane * 4]);
        t.x += zac[12]; t.y += zac[13]; t.z += zac[14]; t.w += zac[15];
        *reinterpret_cast<float4*>(&zrow[768 + lane * 4]) = t;
      }
      __syncthreads();
    }
    {
      // column tid: location within a zred row
      const int wi   = tid & 511;
      const int fidx = ((tid >> 9) * 2 + ((wi & 7) >> 2)) * 256 + (wi >> 3) * 4 + (wi & 3);
      const float s = ((zred[fidx] + zred[KC + fidx]) + zred[2 * KC + fidx]) + zred[3 * KC + fidx];
      AS(&zpart[(size_t)g * VSTR + tid], s);
    }
    if (tid == 0) {
      float zt = 0.0f;
#pragma unroll
      for (int w = 0; w < 16; ++w) zt += ldss[w];
      AS(&zpart[(size_t)g * VSTR + KC], zt);
      float am = ldss[16];
#pragma unroll
      for (int w = 1; w < 16; ++w) am = fmaxf(am, ldss[16 + w]);
      __hip_atomic_fetch_max(ctrl + 320, __float_as_uint(am),
                             __ATOMIC_RELAXED, __HIP_MEMORY_SCOPE_AGENT);
    }
    ++seq; gbar(ctrl, flds, g, tid, seq, 0);

    // ---- P2: owned columns -> b (semi), replicated 8x ----
    if (tid < 256) {
      const float* zb = zpart + (size_t)tid * VSTR + g * CPB;
      const float z0 = AL(zb + 0), z1 = AL(zb + 1), z2 = AL(zb + 2), z3 = AL(zb + 3);
      const float s0 = wave_sum(z0), s1 = wave_sum(z1), s2 = wave_sum(z2), s3 = wave_sum(z3);
      float sl = 0.0f;
      if (g == NBLK - 1) sl = wave_sum(AL(zpart + (size_t)tid * VSTR + KC));
      if (lane == 0) {
        ldss[32 + wv * 4 + 0] = s0; ldss[32 + wv * 4 + 1] = s1;
        ldss[32 + wv * 4 + 2] = s2; ldss[32 + wv * 4 + 3] = s3;
        ldss[48 + wv] = sl;
      }
    }
    __syncthreads();
    if (tid == 0) {
      float bmx = -INFINITY;
#pragma unroll
      for (int c = 0; c < CPB; ++c) {
        const float z    = ((ldss[32 + c] + ldss[36 + c]) + ldss[40 + c]) + ldss[44 + c];
        const float bnew = powf(PBJ / z, FI) * wlds[c];
#pragma unroll
        for (int rep = 0; rep < 8; ++rep) AS(&brep[rep * VSTR + g * CPB + c], bnew);
        bmx = fmaxf(bmx, bnew);
      }
      if (g == NBLK - 1) {
        const float z  = ((ldss[48] + ldss[49]) + ldss[50]) + ldss[51];
        const float bn = PBL / z;
#pragma unroll
        for (int rep = 0; rep < 8; ++rep) AS(&brep[rep * VSTR + KC], bn);
        bmx = fmaxf(bmx, bn);
      }
      __hip_atomic_fetch_max(ctrl + 320, __float_as_uint(bmx),
                             __ATOMIC_RELAXED, __HIP_MEMORY_SCOPE_AGENT);
    }
    ++seq;
    const unsigned fl = gbar(ctrl, flds, g, tid, seq, 1);
    stab = (int)(fl & 1u);
  }

  // ---------------- epilogue ----------------
  bstage[tid] = AL(&brep[rb + tid]);
  if (tid == 0) bstage[KC] = AL(&brep[rb + KC]);
  __syncthreads();

  if (!stab) {
    // plan = n * a_i * Qs_ij * b_j   (Q from LDS; single pass, no barriers)
    float bf[16];
    {
      const float4 t0 = *reinterpret_cast<const float4*>(&bstage[8 * lane]);
      const float4 t1 = *reinterpret_cast<const float4*>(&bstage[8 * lane + 4]);
      const float4 t2 = *reinterpret_cast<const float4*>(&bstage[512 + 8 * lane]);
      const float4 t3 = *reinterpret_cast<const float4*>(&bstage[512 + 8 * lane + 4]);
      bf[0]=t0.x; bf[1]=t0.y; bf[2]=t0.z; bf[3]=t0.w;
      bf[4]=t1.x; bf[5]=t1.y; bf[6]=t1.z; bf[7]=t1.w;
      bf[8]=t2.x; bf[9]=t2.y; bf[10]=t2.z; bf[11]=t2.w;
      bf[12]=t3.x; bf[13]=t3.y; bf[14]=t3.z; bf[15]=t3.w;
    }
#pragma unroll
    for (int r = 0; r < RPW; ++r) {
      const int i  = row0 + r;
      const int lr = wv * RPW + r;
      const float an = ra[lr] * 16384.0f;
      const uint4* qrow = (const uint4*)(Qs + (size_t)lr * KC);
      const uint4 p0 = qrow[lane], p1 = qrow[64 + lane];
      float q[16];
      unpack8(p0, q); unpack8(p1, q + 8);
      float* orow = Qf + (size_t)i * KC;
      *reinterpret_cast<float4*>(orow + 8 * lane) =
        make_float4(an*q[0]*bf[0], an*q[1]*bf[1], an*q[2]*bf[2], an*q[3]*bf[3]);
      *reinterpret_cast<float4*>(orow + 8 * lane + 4) =
        make_float4(an*q[4]*bf[4], an*q[5]*bf[5], an*q[6]*bf[6], an*q[7]*bf[7]);
      *reinterpret_cast<float4*>(orow + 512 + 8 * lane) =
        make_float4(an*q[8]*bf[8], an*q[9]*bf[9], an*q[10]*bf[10], an*q[11]*bf[11]);
      *reinterpret_cast<float4*>(orow + 512 + 8 * lane + 4) =
        make_float4(an*q[12]*bf[12], an*q[13]*bf[13], an*q[14]*bf[14], an*q[15]*bf[15]);
    }
  } else {
    // pending stabilization at exit: plan = n * exp((u2 - cost + v2^T)/eps), from X
    float v2f[16];
#pragma unroll
    for (int e = 0; e < 16; ++e) {
      const int j = (e < 8) ? (8 * lane + e) : (512 + 8 * lane + (e - 8));
      v2f[e] = AL(&varr[vp * VSTR + j]) + EPSF * logf(bstage[j] + TINY);
    }
#pragma unroll
    for (int r = 0; r < RPW; ++r) {
      const int i  = row0 + r;
      const int lr = wv * RPW + r;
      const float u2 = ru[lr] + EPSF * logf(ra[lr]);
      const float mi = rxm[lr], Li = rlr[lr];
      const float* xr = X + (size_t)i * KC;
      float x[16];
      {
        const float4 t0 = *reinterpret_cast<const float4*>(xr + 8 * lane);
        const float4 t1 = *reinterpret_cast<const float4*>(xr + 8 * lane + 4);
        const float4 t2 = *reinterpret_cast<const float4*>(xr + 512 + 8 * lane);
        const float4 t3 = *reinterpret_cast<const float4*>(xr + 512 + 8 * lane + 4);
        x[0]=t0.x; x[1]=t0.y; x[2]=t0.z; x[3]=t0.w;
        x[4]=t1.x; x[5]=t1.y; x[6]=t1.z; x[7]=t1.w;
        x[8]=t2.x; x[9]=t2.y; x[10]=t2.z; x[11]=t2.w;
        x[12]=t3.x; x[13]=t3.y; x[14]=t3.z; x[15]=t3.w;
      }
      float q[16];
#pragma unroll
      for (int e = 0; e < 16; ++e)
        q[e] = expf((u2 - (Li - (x[e] - mi)) + v2f[e]) / EPSF) * 16384.0f;
      float* orow = Qf + (size_t)i * KC;
      *reinterpret_cast<float4*>(orow + 8 * lane)           = make_float4(q[0], q[1], q[2], q[3]);
      *reinterpret_cast<float4*>(orow + 8 * lane + 4)       = make_float4(q[4], q[5], q[6], q[7]);
      *reinterpret_cast<float4*>(orow + 512 + 8 * lane)     = make_float4(q[8], q[9], q[10], q[11]);
      *reinterpret_cast<float4*>(orow + 512 + 8 * lane + 4) = make_float4(q[12], q[13], q[14], q[15]);
    }
  }
}

extern "C" void kernel_launch(void* const* d_in, const int* in_sizes, int n_in,
                              void* d_out, int out_size, void* d_ws, size_t ws_size,
                              hipStream_t stream)
{
  (void)in_sizes; (void)n_in; (void)out_size; (void)ws_size;
  const float* X = (const float*)d_in[0];
  float* Qf = (float*)d_out;
  hipMemsetAsync(d_ws, 0, 4096, stream);   // barrier counters, gmax, release flags
  void* args[3] = { (void*)&X, (void*)&Qf, (void*)&d_ws };
  hipLaunchCooperativeKernel((const void*)sk_coop, dim3(NBLK), dim3(NTHR),
                             args, 0, stream);
}

// Round 7
// 14657.143 us; speedup vs baseline: 5.2956x; 1.1905x over previous
//
#include <hip/hip_runtime.h>
#include <math.h>

#define NROWS 16384
#define KC    1024
#define NBLK  256
#define NTHR  1024
#define WPB   16      // waves per block
#define RPW   4       // rows per wave; 64 rows per block
#define CPB   4       // regular columns owned per block (block 255 also owns col 1024)
#define VSTR  1056    // padded stride for (K+1)-length vectors
#define NITER 1000

// relaxed agent-scope (device-coherent) access
#define AL(p)    __hip_atomic_load((p), __ATOMIC_RELAXED, __HIP_MEMORY_SCOPE_AGENT)
#define AS(p,v)  __hip_atomic_store((p), (v), __ATOMIC_RELAXED, __HIP_MEMORY_SCOPE_AGENT)

__device__ __forceinline__ float wave_sum(float v) {
#pragma unroll
  for (int o = 32; o > 0; o >>= 1) v += __shfl_xor(v, o, 64);
  return v;
}
__device__ __forceinline__ float wave_max(float v) {
#pragma unroll
  for (int o = 32; o > 0; o >>= 1) v = fmaxf(v, __shfl_xor(v, o, 64));
  return v;
}

// bf16 pack/unpack (RNE)
__device__ __forceinline__ unsigned short f2b(float f) {
  unsigned u = __float_as_uint(f);
  u += 0x7FFFu + ((u >> 16) & 1u);
  return (unsigned short)(u >> 16);
}
__device__ __forceinline__ float b2f(unsigned h) {
  return __uint_as_float(h << 16);
}
__device__ __forceinline__ void unpack8(const uint4 p, float* f) {
  f[0] = b2f(p.x & 0xffffu); f[1] = b2f(p.x >> 16);
  f[2] = b2f(p.y & 0xffffu); f[3] = b2f(p.y >> 16);
  f[4] = b2f(p.z & 0xffffu); f[5] = b2f(p.z >> 16);
  f[6] = b2f(p.w & 0xffffu); f[7] = b2f(p.w >> 16);
}
__device__ __forceinline__ uint4 pack8(const float* f) {
  uint4 p;
  p.x = (unsigned)f2b(f[0]) | ((unsigned)f2b(f[1]) << 16);
  p.y = (unsigned)f2b(f[2]) | ((unsigned)f2b(f[3]) << 16);
  p.z = (unsigned)f2b(f[4]) | ((unsigned)f2b(f[5]) << 16);
  p.w = (unsigned)f2b(f[6]) | ((unsigned)f2b(f[7]) << 16);
  return p;
}

// Store-based master-sweep barrier (no RMWs on the critical path).
// ctrl (uints): arr[256] at words 0..255 (block g stores monotonic seq);
// gmax at word 288; release replicas at words 320 + i*32 (i=0..7).
// Release value = seq*2 | stab.
__device__ __forceinline__ unsigned gbar(unsigned* ctrl, unsigned* flds,
                                         int g, int tid, unsigned seq, int isb2) {
  __syncthreads();   // all waves' vmem (incl. coherent stores) drained before arrival
  if (g == 0) {
    // master: 255 threads each poll one arrival flag (coalesced flag array)
    if (tid >= 1 && tid < 256) {
      while (AL(&ctrl[tid]) < seq) __builtin_amdgcn_s_sleep(1);
    }
    __syncthreads();   // all arrivals observed
    if (tid == 0) {
      unsigned stab = 0u;
      if (isb2) {
        const unsigned gm = AL(ctrl + 288);
        stab = (__uint_as_float(gm) > 1e8f) ? 1u : 0u;
        AS(ctrl + 288, 0u);
        asm volatile("s_waitcnt vmcnt(0)" ::: "memory");  // reset visible before release
      }
      const unsigned fl = seq * 2u + stab;
#pragma unroll
      for (int i = 0; i < 8; ++i) AS(ctrl + 320 + i * 32, fl);
      flds[0] = fl;
    }
    __syncthreads();
  } else {
    if (tid == 0) {
      AS(&ctrl[g], seq);           // arrival store (after this wave's vmcnt drain)
      unsigned fl;
      unsigned* myf = ctrl + 320 + (((unsigned)g) & 7u) * 32;
      for (;;) {
        fl = AL(myf);
        if (fl >= seq * 2u) break;
        __builtin_amdgcn_s_sleep(1);
      }
      flds[0] = fl;
    }
    __syncthreads();
  }
  return flds[0];
}

// Lane-column mapping: lane l owns cols [8l, 8l+8) and [512+8l, 512+8l+8).
// zred row layout (1024 floats): chunk k (0..3) at [k*256 + lane*4 .. +3]:
//   k=0: cols 8l..8l+3, k=1: 8l+4..8l+7, k=2: 512+8l..+3, k=3: 512+8l+4..+7
__global__ __launch_bounds__(NTHR, 4)
void sk_coop(const float* __restrict__ X, float* __restrict__ Qf, void* __restrict__ wsv)
{
  const int g    = blockIdx.x;
  const int tid  = threadIdx.x;
  const int wv   = tid >> 6;
  const int lane = tid & 63;
  const int row0 = (g * WPB + wv) * RPW;   // global row base for this wave
  const unsigned rb = (((unsigned)g) & 7u) * VSTR;

  unsigned* ctrl = (unsigned*)wsv;
  float* varr  = (float*)((char*)wsv + 4096); // [2*VSTR] dual potentials (ping-pong)
  float* brep  = varr + 2 * VSTR;             // [8][VSTR] b replicas
  float* zpart = brep + 8 * VSTR;             // [NBLK][VSTR]

  // ---- LDS: whole Q tile resident across the loop (131 KB) ----
  __shared__ unsigned short Qs[64 * KC];      // bf16, row lr at Qs + lr*KC
  __shared__ float zred[4 * KC];              // 16 KB z accumulate (4 rows)
  __shared__ float bstage[VSTR];
  __shared__ float rq[64], rxm[64], rlr[64], ra[64], ru[64];  // per-local-row state
  __shared__ float wlds[CPB];
  __shared__ float ldss[64];
  __shared__ unsigned flds[1];

  const float FI   = (float)(1.0 / 1.1);
  const float FIM1 = (float)(1.0 / 1.1 - 1.0);
  const float TINY = 1.1920928955078125e-07f;
  const float PA   = 1.0f / 16384.0f;
  const float PBJ  = 0.5f / 1024.0f;
  const float PBL  = 0.5f;
  const float EPSF = 0.1f;

  // ---------------- init: softmax stats + Q0 (bf16) into LDS ----------------
  if (tid < CPB) {
    AS(&varr[g * CPB + tid], 0.0f);
    AS(&varr[VSTR + g * CPB + tid], 0.0f);
    wlds[tid] = 1.0f;
  }
  if (g == NBLK - 1 && tid == CPB) { AS(&varr[KC], 0.0f); AS(&varr[VSTR + KC], 0.0f); }
#pragma unroll
  for (int r = 0; r < RPW; ++r) {
    const int i  = row0 + r;
    const int lr = wv * RPW + r;
    const float* xr = X + (size_t)i * KC;
    float x[16];
    {
      const float4 t0 = *reinterpret_cast<const float4*>(xr + 8 * lane);
      const float4 t1 = *reinterpret_cast<const float4*>(xr + 8 * lane + 4);
      const float4 t2 = *reinterpret_cast<const float4*>(xr + 512 + 8 * lane);
      const float4 t3 = *reinterpret_cast<const float4*>(xr + 512 + 8 * lane + 4);
      x[0]=t0.x; x[1]=t0.y; x[2]=t0.z; x[3]=t0.w;
      x[4]=t1.x; x[5]=t1.y; x[6]=t1.z; x[7]=t1.w;
      x[8]=t2.x; x[9]=t2.y; x[10]=t2.z; x[11]=t2.w;
      x[12]=t3.x; x[13]=t3.y; x[14]=t3.z; x[15]=t3.w;
    }
    float mx = -INFINITY;
#pragma unroll
    for (int e = 0; e < 16; ++e) mx = fmaxf(mx, x[e]);
    mx = wave_max(mx);
    float s = 0.0f;
#pragma unroll
    for (int e = 0; e < 16; ++e) s += expf(x[e] - mx);
    s = wave_sum(s);
    const float L = logf(s);
    if (lane == 0) { rxm[lr] = mx; rlr[lr] = L; ru[lr] = 0.0f; rq[lr] = 1.0f; }
    float q[16];
#pragma unroll
    for (int e = 0; e < 16; ++e) q[e] = expf(((x[e] - mx) - L) / EPSF);
    uint4* qrow = (uint4*)(Qs + (size_t)lr * KC);
    qrow[lane]      = pack8(q);
    qrow[64 + lane] = pack8(q + 8);
  }
  // no global sync needed before iter 0: b(0) is constant, Q rows are wave-local

  // ---------------- main loop ----------------
  int vp = 0, stab = 0;
  unsigned seq = 0;

  for (int it = 0; it < NITER; ++it) {
    // ---- stage b into LDS ----
    if (it == 0) {
      bstage[tid] = 1.0f / 1025.0f;
      if (tid == 0) bstage[KC] = 1.0f / 1025.0f;
    } else {
      bstage[tid] = AL(&brep[rb + tid]);
      if (tid == 0) bstage[KC] = AL(&brep[rb + KC]);
    }
    __syncthreads();

    float zac[16];
#pragma unroll
    for (int e = 0; e < 16; ++e) zac[e] = 0.0f;
    float zl = 0.0f, amx = -INFINITY;

    float bf[16];
    {
      const float4 t0 = *reinterpret_cast<const float4*>(&bstage[8 * lane]);
      const float4 t1 = *reinterpret_cast<const float4*>(&bstage[8 * lane + 4]);
      const float4 t2 = *reinterpret_cast<const float4*>(&bstage[512 + 8 * lane]);
      const float4 t3 = *reinterpret_cast<const float4*>(&bstage[512 + 8 * lane + 4]);
      bf[0]=t0.x; bf[1]=t0.y; bf[2]=t0.z; bf[3]=t0.w;
      bf[4]=t1.x; bf[5]=t1.y; bf[6]=t1.z; bf[7]=t1.w;
      bf[8]=t2.x; bf[9]=t2.y; bf[10]=t2.z; bf[11]=t2.w;
      bf[12]=t3.x; bf[13]=t3.y; bf[14]=t3.z; bf[15]=t3.w;
    }
    const float bl = bstage[KC];

    if (!stab) {
      // ---- P1 from LDS: y = Q b ; a = Pa/y ; z += a_i * Q_i ----
#pragma unroll
      for (int r = 0; r < RPW; ++r) {
        const int lr = wv * RPW + r;
        const uint4* qrow = (const uint4*)(Qs + (size_t)lr * KC);
        const uint4 p0 = qrow[lane], p1 = qrow[64 + lane];
        float q[16];
        unpack8(p0, q); unpack8(p1, q + 8);
        float d = 0.0f;
#pragma unroll
        for (int e = 0; e < 16; ++e) d = fmaf(q[e], bf[e], d);
        const float ql = rq[lr];
        const float y  = wave_sum(d) + ql * bl;
        const float ai = PA / y;
        if (lane == 0) ra[lr] = ai;
        amx = fmaxf(amx, ai);
#pragma unroll
        for (int e = 0; e < 16; ++e) zac[e] = fmaf(ai, q[e], zac[e]);
        zl = fmaf(ai, ql, zl);
      }
    } else {
      // ---- P1 deferred stabilization: rewrite Q (LDS) from logits; b := ones ----
      if (tid < CPB) {
        const int j = g * CPB + tid;
        const float bj = bstage[j];
        AS(&varr[(vp ^ 1) * VSTR + j], AL(&varr[vp * VSTR + j]) + EPSF * logf(bj + TINY));
        wlds[tid] = wlds[tid] * powf(bj, FIM1);
      }
      if (g == NBLK - 1 && tid == CPB)
        AS(&varr[(vp ^ 1) * VSTR + KC], AL(&varr[vp * VSTR + KC]) + EPSF * logf(bstage[KC] + TINY));
      float v2f[16];
#pragma unroll
      for (int e = 0; e < 16; ++e) {
        const int j = (e < 8) ? (8 * lane + e) : (512 + 8 * lane + (e - 8));
        v2f[e] = AL(&varr[vp * VSTR + j]) + EPSF * logf(bstage[j] + TINY);
      }
      const float v2l = AL(&varr[vp * VSTR + KC]) + EPSF * logf(bstage[KC] + TINY);
#pragma unroll
      for (int r = 0; r < RPW; ++r) {
        const int i  = row0 + r;
        const int lr = wv * RPW + r;
        const float u2 = ru[lr] + EPSF * logf(ra[lr]);
        if (lane == 0) ru[lr] = u2;
        const float mi = rxm[lr], Li = rlr[lr];
        const float* xr = X + (size_t)i * KC;
        float q[16];
        {
          const float4 t0 = *reinterpret_cast<const float4*>(xr + 8 * lane);
          const float4 t1 = *reinterpret_cast<const float4*>(xr + 8 * lane + 4);
          const float4 t2 = *reinterpret_cast<const float4*>(xr + 512 + 8 * lane);
          const float4 t3 = *reinterpret_cast<const float4*>(xr + 512 + 8 * lane + 4);
          q[0]=t0.x; q[1]=t0.y; q[2]=t0.z; q[3]=t0.w;
          q[4]=t1.x; q[5]=t1.y; q[6]=t1.z; q[7]=t1.w;
          q[8]=t2.x; q[9]=t2.y; q[10]=t2.z; q[11]=t2.w;
          q[12]=t3.x; q[13]=t3.y; q[14]=t3.z; q[15]=t3.w;
        }
#pragma unroll
        for (int e = 0; e < 16; ++e) {
          const float cost = Li - (q[e] - mi);
          q[e] = expf((u2 - cost + v2f[e]) / EPSF);
        }
        uint4* qrow = (uint4*)(Qs + (size_t)lr * KC);
        qrow[lane]      = pack8(q);
        qrow[64 + lane] = pack8(q + 8);
        float d = 0.0f;
#pragma unroll
        for (int e = 0; e < 16; ++e) d += q[e];
        const float ql = expf((u2 + v2l) / EPSF);
        if (lane == 0) rq[lr] = ql;
        const float y  = wave_sum(d) + ql;
        const float ai = PA / y;
        if (lane == 0) ra[lr] = ai;
        amx = fmaxf(amx, ai);
#pragma unroll
        for (int e = 0; e < 16; ++e) zac[e] = fmaf(ai, q[e], zac[e]);
        zl = fmaf(ai, ql, zl);
      }
      vp ^= 1;
    }

    // ---- z reduce: 4-phase accumulate into zred[4][KC] (conflict-free layout) ----
    const float wamx = wave_max(amx);
    if (lane == 0) { ldss[wv] = zl; ldss[16 + wv] = wamx; }
    float* zrow = zred + (wv & 3) * KC;
    const int gp = wv >> 2;
    __syncthreads();
    if (gp == 0) {
      *reinterpret_cast<float4*>(&zrow[lane * 4])       = make_float4(zac[0], zac[1], zac[2], zac[3]);
      *reinterpret_cast<float4*>(&zrow[256 + lane * 4]) = make_float4(zac[4], zac[5], zac[6], zac[7]);
      *reinterpret_cast<float4*>(&zrow[512 + lane * 4]) = make_float4(zac[8], zac[9], zac[10], zac[11]);
      *reinterpret_cast<float4*>(&zrow[768 + lane * 4]) = make_float4(zac[12], zac[13], zac[14], zac[15]);
    }
    __syncthreads();
#pragma unroll
    for (int p = 1; p < 4; ++p) {
      if (gp == p) {
        float4 t;
        t = *reinterpret_cast<float4*>(&zrow[lane * 4]);
        t.x += zac[0]; t.y += zac[1]; t.z += zac[2]; t.w += zac[3];
        *reinterpret_cast<float4*>(&zrow[lane * 4]) = t;
        t = *reinterpret_cast<float4*>(&zrow[256 + lane * 4]);
        t.x += zac[4]; t.y += zac[5]; t.z += zac[6]; t.w += zac[7];
        *reinterpret_cast<float4*>(&zrow[256 + lane * 4]) = t;
        t = *reinterpret_cast<float4*>(&zrow[512 + lane * 4]);
        t.x += zac[8]; t.y += zac[9]; t.z += zac[10]; t.w += zac[11];
        *reinterpret_cast<float4*>(&zrow[512 + lane * 4]) = t;
        t = *reinterpret_cast<float4*>(&zrow[768 + lane * 4]);
        t.x += zac[12]; t.y += zac[13]; t.z += zac[14]; t.w += zac[15];
        *reinterpret_cast<float4*>(&zrow[768 + lane * 4]) = t;
      }
      __syncthreads();
    }
    {
      // column tid: location within a zred row
      const int wi   = tid & 511;
      const int fidx = ((tid >> 9) * 2 + ((wi & 7) >> 2)) * 256 + (wi >> 3) * 4 + (wi & 3);
      const float s = ((zred[fidx] + zred[KC + fidx]) + zred[2 * KC + fidx]) + zred[3 * KC + fidx];
      AS(&zpart[(size_t)g * VSTR + tid], s);
    }
    if (tid == 0) {
      float zt = 0.0f;
#pragma unroll
      for (int w = 0; w < 16; ++w) zt += ldss[w];
      AS(&zpart[(size_t)g * VSTR + KC], zt);
      float am = ldss[16];
#pragma unroll
      for (int w = 1; w < 16; ++w) am = fmaxf(am, ldss[16 + w]);
      __hip_atomic_fetch_max(ctrl + 288, __float_as_uint(am),
                             __ATOMIC_RELAXED, __HIP_MEMORY_SCOPE_AGENT);
    }
    ++seq; gbar(ctrl, flds, g, tid, seq, 0);

    // ---- P2: owned columns -> b (semi), replicated 8x ----
    if (tid < 256) {
      const float* zb = zpart + (size_t)tid * VSTR + g * CPB;
      const float z0 = AL(zb + 0), z1 = AL(zb + 1), z2 = AL(zb + 2), z3 = AL(zb + 3);
      const float s0 = wave_sum(z0), s1 = wave_sum(z1), s2 = wave_sum(z2), s3 = wave_sum(z3);
      float sl = 0.0f;
      if (g == NBLK - 1) sl = wave_sum(AL(zpart + (size_t)tid * VSTR + KC));
      if (lane == 0) {
        ldss[32 + wv * 4 + 0] = s0; ldss[32 + wv * 4 + 1] = s1;
        ldss[32 + wv * 4 + 2] = s2; ldss[32 + wv * 4 + 3] = s3;
        ldss[48 + wv] = sl;
      }
    }
    __syncthreads();
    if (tid == 0) {
      float bmx = -INFINITY;
#pragma unroll
      for (int c = 0; c < CPB; ++c) {
        const float z    = ((ldss[32 + c] + ldss[36 + c]) + ldss[40 + c]) + ldss[44 + c];
        const float bnew = powf(PBJ / z, FI) * wlds[c];
#pragma unroll
        for (int rep = 0; rep < 8; ++rep) AS(&brep[rep * VSTR + g * CPB + c], bnew);
        bmx = fmaxf(bmx, bnew);
      }
      if (g == NBLK - 1) {
        const float z  = ((ldss[48] + ldss[49]) + ldss[50]) + ldss[51];
        const float bn = PBL / z;
#pragma unroll
        for (int rep = 0; rep < 8; ++rep) AS(&brep[rep * VSTR + KC], bn);
        bmx = fmaxf(bmx, bn);
      }
      __hip_atomic_fetch_max(ctrl + 288, __float_as_uint(bmx),
                             __ATOMIC_RELAXED, __HIP_MEMORY_SCOPE_AGENT);
    }
    ++seq;
    const unsigned fl = gbar(ctrl, flds, g, tid, seq, 1);
    stab = (int)(fl & 1u);
  }

  // ---------------- epilogue ----------------
  bstage[tid] = AL(&brep[rb + tid]);
  if (tid == 0) bstage[KC] = AL(&brep[rb + KC]);
  __syncthreads();

  if (!stab) {
    // plan = n * a_i * Qs_ij * b_j   (Q from LDS; single pass, no barriers)
    float bf[16];
    {
      const float4 t0 = *reinterpret_cast<const float4*>(&bstage[8 * lane]);
      const float4 t1 = *reinterpret_cast<const float4*>(&bstage[8 * lane + 4]);
      const float4 t2 = *reinterpret_cast<const float4*>(&bstage[512 + 8 * lane]);
      const float4 t3 = *reinterpret_cast<const float4*>(&bstage[512 + 8 * lane + 4]);
      bf[0]=t0.x; bf[1]=t0.y; bf[2]=t0.z; bf[3]=t0.w;
      bf[4]=t1.x; bf[5]=t1.y; bf[6]=t1.z; bf[7]=t1.w;
      bf[8]=t2.x; bf[9]=t2.y; bf[10]=t2.z; bf[11]=t2.w;
      bf[12]=t3.x; bf[13]=t3.y; bf[14]=t3.z; bf[15]=t3.w;
    }
#pragma unroll
    for (int r = 0; r < RPW; ++r) {
      const int i  = row0 + r;
      const int lr = wv * RPW + r;
      const float an = ra[lr] * 16384.0f;
      const uint4* qrow = (const uint4*)(Qs + (size_t)lr * KC);
      const uint4 p0 = qrow[lane], p1 = qrow[64 + lane];
      float q[16];
      unpack8(p0, q); unpack8(p1, q + 8);
      float* orow = Qf + (size_t)i * KC;
      *reinterpret_cast<float4*>(orow + 8 * lane) =
        make_float4(an*q[0]*bf[0], an*q[1]*bf[1], an*q[2]*bf[2], an*q[3]*bf[3]);
      *reinterpret_cast<float4*>(orow + 8 * lane + 4) =
        make_float4(an*q[4]*bf[4], an*q[5]*bf[5], an*q[6]*bf[6], an*q[7]*bf[7]);
      *reinterpret_cast<float4*>(orow + 512 + 8 * lane) =
        make_float4(an*q[8]*bf[8], an*q[9]*bf[9], an*q[10]*bf[10], an*q[11]*bf[11]);
      *reinterpret_cast<float4*>(orow + 512 + 8 * lane + 4) =
        make_float4(an*q[12]*bf[12], an*q[13]*bf[13], an*q[14]*bf[14], an*q[15]*bf[15]);
    }
  } else {
    // pending stabilization at exit: plan = n * exp((u2 - cost + v2^T)/eps), from X
    float v2f[16];
#pragma unroll
    for (int e = 0; e < 16; ++e) {
      const int j = (e < 8) ? (8 * lane + e) : (512 + 8 * lane + (e - 8));
      v2f[e] = AL(&varr[vp * VSTR + j]) + EPSF * logf(bstage[j] + TINY);
    }
#pragma unroll
    for (int r = 0; r < RPW; ++r) {
      const int i  = row0 + r;
      const int lr = wv * RPW + r;
      const float u2 = ru[lr] + EPSF * logf(ra[lr]);
      const float mi = rxm[lr], Li = rlr[lr];
      const float* xr = X + (size_t)i * KC;
      float x[16];
      {
        const float4 t0 = *reinterpret_cast<const float4*>(xr + 8 * lane);
        const float4 t1 = *reinterpret_cast<const float4*>(xr + 8 * lane + 4);
        const float4 t2 = *reinterpret_cast<const float4*>(xr + 512 + 8 * lane);
        const float4 t3 = *reinterpret_cast<const float4*>(xr + 512 + 8 * lane + 4);
        x[0]=t0.x; x[1]=t0.y; x[2]=t0.z; x[3]=t0.w;
        x[4]=t1.x; x[5]=t1.y; x[6]=t1.z; x[7]=t1.w;
        x[8]=t2.x; x[9]=t2.y; x[10]=t2.z; x[11]=t2.w;
        x[12]=t3.x; x[13]=t3.y; x[14]=t3.z; x[15]=t3.w;
      }
      float q[16];
#pragma unroll
      for (int e = 0; e < 16; ++e)
        q[e] = expf((u2 - (Li - (x[e] - mi)) + v2f[e]) / EPSF) * 16384.0f;
      float* orow = Qf + (size_t)i * KC;
      *reinterpret_cast<float4*>(orow + 8 * lane)           = make_float4(q[0], q[1], q[2], q[3]);
      *reinterpret_cast<float4*>(orow + 8 * lane + 4)       = make_float4(q[4], q[5], q[6], q[7]);
      *reinterpret_cast<float4*>(orow + 512 + 8 * lane)     = make_float4(q[8], q[9], q[10], q[11]);
      *reinterpret_cast<float4*>(orow + 512 + 8 * lane + 4) = make_float4(q[12], q[13], q[14], q[15]);
    }
  }
}

extern "C" void kernel_launch(void* const* d_in, const int* in_sizes, int n_in,
                              void* d_out, int out_size, void* d_ws, size_t ws_size,
                              hipStream_t stream)
{
  (void)in_sizes; (void)n_in; (void)out_size; (void)ws_size;
  const float* X = (const float*)d_in[0];
  float* Qf = (float*)d_out;
  hipMemsetAsync(d_ws, 0, 4096, stream);   // arrival flags, gmax, release replicas
  void* args[3] = { (void*)&X, (void*)&Qf, (void*)&d_ws };
  hipLaunchCooperativeKernel((const void*)sk_coop, dim3(NBLK), dim3(NTHR),
                             args, 0, stream);
}